// Round 1
// baseline (876.112 us; speedup 1.0000x reference)
//
#include <hip/hip_runtime.h>
#include <hip/hip_bf16.h>

#define BATCH 2
#define SEQ 1024
#define DIM 1024
#define DINNER 2048
#define NSTATE 16
#define DTRANK 64
#define NDBL 96
#define ROWS (BATCH*SEQ)

typedef __attribute__((ext_vector_type(8))) short bf16x8;
typedef __attribute__((ext_vector_type(4))) float f32x4;

__device__ inline float wave_sum64(float v){
#pragma unroll
  for (int o=32;o>0;o>>=1) v += __shfl_xor(v,o,64);
  return v;
}
__device__ inline float wave_max64(float v){
#pragma unroll
  for (int o=32;o>0;o>>=1) v = fmaxf(v,__shfl_xor(v,o,64));
  return v;
}
__device__ inline float block_sum256(float v, float* sred){
  v = wave_sum64(v);
  if ((threadIdx.x&63)==0) sred[threadIdx.x>>6]=v;
  __syncthreads();
  float t = sred[0]+sred[1]+sred[2]+sred[3];
  __syncthreads();
  return t;
}
__device__ inline float block_max256(float v, float* sred){
  v = wave_max64(v);
  if ((threadIdx.x&63)==0) sred[threadIdx.x>>6]=v;
  __syncthreads();
  float t = fmaxf(fmaxf(sred[0],sred[1]),fmaxf(sred[2],sred[3]));
  __syncthreads();
  return t;
}

// ---------- weight ternarization ----------
__global__ __launch_bounds__(256) void absmean_partial_k(const float* __restrict__ w, int n,
                                                         float* __restrict__ part){
  __shared__ float sred[4];
  float s = 0.f;
  for (int i = blockIdx.x*256 + threadIdx.x; i < n; i += 512*256) s += fabsf(w[i]);
  s = block_sum256(s, sred);
  if (threadIdx.x==0) part[blockIdx.x] = s;
}
__global__ __launch_bounds__(256) void absmean_final_k(const float* __restrict__ part,
                                                       float count, float* __restrict__ out){
  __shared__ float sred[4];
  float s = part[threadIdx.x] + part[threadIdx.x+256];
  s = block_sum256(s, sred);
  if (threadIdx.x==0) *out = fmaxf(s/count, 1e-5f);
}
__global__ __launch_bounds__(256) void ternarize_k(const float* __restrict__ w,
                                                   __hip_bfloat16* __restrict__ wq, int n,
                                                   const float* __restrict__ scale){
  int i = blockIdx.x*256 + threadIdx.x;
  if (i<n){
    float q = rintf(w[i] / *scale);
    q = fminf(fmaxf(q,-1.f),1.f);
    wq[i] = __float2bfloat16(q);
  }
}

// ---------- fused (optional rms_norm) + LayerNorm + activation int8 fake-quant ----------
template<int NV>
__global__ __launch_bounds__(256) void ln_quant_k(const float* __restrict__ src,
    const float* __restrict__ rmsw, __hip_bfloat16* __restrict__ q, float* __restrict__ rs){
  constexpr int C = NV*256;
  __shared__ float sred[4];
  const int r = blockIdx.x, tid = threadIdx.x;
  const float* row = src + (size_t)r*C;
  float v[NV];
#pragma unroll
  for (int i=0;i<NV;i++) v[i] = row[tid + i*256];
  if (rmsw){
    float ss=0.f;
#pragma unroll
    for (int i=0;i<NV;i++) ss += v[i]*v[i];
    ss = block_sum256(ss, sred);
    float f = rsqrtf(ss/(float)C + 1e-6f);
#pragma unroll
    for (int i=0;i<NV;i++) v[i] *= f * rmsw[tid + i*256];
  }
  float s=0.f;
#pragma unroll
  for (int i=0;i<NV;i++) s += v[i];
  s = block_sum256(s, sred);
  const float mu = s/(float)C;
  float vs=0.f;
#pragma unroll
  for (int i=0;i<NV;i++){ float d=v[i]-mu; vs += d*d; }
  vs = block_sum256(vs, sred);
  const float inv = rsqrtf(vs/(float)C + 1e-5f);
  float am=0.f;
#pragma unroll
  for (int i=0;i<NV;i++){ v[i] = (v[i]-mu)*inv; am = fmaxf(am, fabsf(v[i])); }
  am = block_max256(am, sred);
  am = fmaxf(am, 1e-5f);
  const float scale = 127.f/am;
  if (tid==0) rs[r] = am*(1.f/127.f);
#pragma unroll
  for (int i=0;i<NV;i++){
    float qv = fminf(fmaxf(rintf(v[i]*scale), -128.f), 127.f);
    q[(size_t)r*C + tid + i*256] = __float2bfloat16(qv);
  }
}

// ---------- bf16 MFMA GEMM: C[M,N] = rs[m] * sum_k A[m,k]*B[n,k] ----------
// mode 0: out0[r*ldc+n] (guard n<Nact); mode 1: split n<2048->out0, else out1;
// mode 2: out0[r*ldc+n] = hid[..] + v
__global__ __launch_bounds__(256) void gemm_q_k(
    const short* __restrict__ A, const short* __restrict__ Bw,
    const float* __restrict__ rs, int K, int Nact, int mode, int ldc,
    float* __restrict__ out0, float* __restrict__ out1,
    const float* __restrict__ hid)
{
  __shared__ short lsA[128*32];
  __shared__ short lsB[128*32];
  const int tid = threadIdx.x;
  const int w = tid>>6, l = tid&63;
  const int m0 = blockIdx.x*128, n0 = blockIdx.y*128;
  const int wr = (w>>1)*64, wc = (w&1)*64;
  f32x4 acc[4][4];
#pragma unroll
  for (int m=0;m<4;m++)
#pragma unroll
    for (int n=0;n<4;n++) acc[m][n] = (f32x4){0.f,0.f,0.f,0.f};

  const size_t KB = (size_t)K*2;
  const char* Ag = (const char*)A + (size_t)m0*KB;
  const char* Bg = (const char*)Bw + (size_t)n0*KB;
  const int lr = l&15, lk = (l>>4)*16;

  for (int kk=0; kk<K; kk+=32){
    __syncthreads();
#pragma unroll
    for (int c0=0;c0<2;c0++){
      int c = tid + c0*256;
      int o = c<<4;
      int rrow = o>>6, x = o&63;
      bf16x8 va = *(const bf16x8*)(Ag + (size_t)rrow*KB + (size_t)kk*2 + x);
      bf16x8 vb = *(const bf16x8*)(Bg + (size_t)rrow*KB + (size_t)kk*2 + x);
      *(bf16x8*)((char*)lsA + o) = va;
      *(bf16x8*)((char*)lsB + o) = vb;
    }
    __syncthreads();
    bf16x8 af[4], bb[4];
#pragma unroll
    for (int m=0;m<4;m++) af[m] = *(const bf16x8*)((const char*)lsA + (size_t)(wr + m*16 + lr)*64 + lk);
#pragma unroll
    for (int n=0;n<4;n++) bb[n] = *(const bf16x8*)((const char*)lsB + (size_t)(wc + n*16 + lr)*64 + lk);
#pragma unroll
    for (int m=0;m<4;m++)
#pragma unroll
      for (int n=0;n<4;n++)
        acc[m][n] = __builtin_amdgcn_mfma_f32_16x16x32_bf16(af[m], bb[n], acc[m][n], 0, 0, 0);
  }

  const int lg = l>>4;
#pragma unroll
  for (int m=0;m<4;m++){
    const int rowb = m0 + wr + m*16 + lg*4;
#pragma unroll
    for (int j=0;j<4;j++){
      const int row = rowb + j;
      const float rsv = rs[row];
#pragma unroll
      for (int n=0;n<4;n++){
        const int col = n0 + wc + n*16 + lr;
        const float v = acc[m][n][j]*rsv;
        if (mode==1){
          if (col < 2048) out0[(size_t)row*2048 + col] = v;
          else            out1[(size_t)row*2048 + (col-2048)] = v;
        } else if (mode==2){
          const size_t o = (size_t)row*ldc + col;
          out0[o] = hid[o] + v;
        } else {
          if (col < Nact) out0[(size_t)row*ldc + col] = v;
        }
      }
    }
  }
}

// ---------- depthwise causal conv1d (k=4) + bias + silu ----------
__global__ __launch_bounds__(256) void conv_silu_k(const float* __restrict__ x,
    const float* __restrict__ cw, const float* __restrict__ cb, float* __restrict__ xc){
  const int idx = blockIdx.x*256 + threadIdx.x;
  const int d = idx & (DINNER-1);
  const int t = (idx>>11) & (SEQ-1);
  const int b = idx>>21;
  const float* wd = cw + (size_t)d*4;
  float acc = cb[d];
#pragma unroll
  for (int j=0;j<4;j++){
    const int tt = t-3+j;
    if (tt>=0) acc += x[((size_t)(b*SEQ+tt))*DINNER + d]*wd[j];
  }
  xc[(size_t)idx] = acc/(1.f+expf(-acc));
}

// ---------- dt = xdbl[:, :64] @ W^T + 2b ; delta = softplus(dt) ----------
__global__ __launch_bounds__(256) void dt_delta_k(const float* __restrict__ xdbl,
    const float* __restrict__ W, const float* __restrict__ bias, float* __restrict__ delta){
  __shared__ float sW[64][65];
  __shared__ float sX[32][64];
  const int tid = threadIdx.x;
  const int r0 = blockIdx.x*32, d0 = blockIdx.y*64;
  for (int i=tid;i<64*64;i+=256){ int rr=i>>6, cc=i&63; sW[rr][cc] = W[(size_t)(d0+rr)*64+cc]; }
  for (int i=tid;i<32*64;i+=256){ int rr=i>>6, cc=i&63; sX[rr][cc] = xdbl[(size_t)(r0+rr)*NDBL+cc]; }
  __syncthreads();
  const int dl = tid&63, ty = tid>>6;
  const float b2 = 2.f*bias[d0+dl];
  float acc[8];
#pragma unroll
  for (int i=0;i<8;i++) acc[i]=0.f;
#pragma unroll 8
  for (int k=0;k<64;k++){
    const float wv = sW[dl][k];
#pragma unroll
    for (int i=0;i<8;i++) acc[i] += sX[ty*8+i][k]*wv;
  }
#pragma unroll
  for (int i=0;i<8;i++){
    const float xq = acc[i] + b2;
    const float sp = (xq>20.f) ? xq : log1pf(expf(xq));
    delta[(size_t)(r0+ty*8+i)*DINNER + d0+dl] = sp;
  }
}

// ---------- selective scan; y written in place over z ----------
__global__ __launch_bounds__(256) void scan_k(const float* __restrict__ delta,
    const float* __restrict__ xc, const float* __restrict__ xdbl,
    const float* __restrict__ A_log, const float* __restrict__ Dp,
    float* __restrict__ zy){
  const int tid = threadIdx.x;
  const int n = tid&15;
  const int ch = blockIdx.x*16 + (tid>>4);
  const int b = ch>>11, d = ch&(DINNER-1);
  const float a = -expf(A_log[(size_t)d*NSTATE+n]);
  const float Dv = Dp[d];
  const size_t rb = (size_t)b*SEQ;
  float h = 0.f;
  float dl = delta[rb*DINNER + d];
  float xv = xc[rb*DINNER + d];
  float Bv = xdbl[rb*NDBL + DTRANK + n];
  float Cv = xdbl[rb*NDBL + DTRANK + NSTATE + n];
  for (int t=0;t<SEQ;t++){
    const float dlc=dl, xvc=xv, Bvc=Bv, Cvc=Cv;
    if (t < SEQ-1){
      const size_t r2 = rb + t + 1;
      dl = delta[r2*DINNER + d];
      xv = xc[r2*DINNER + d];
      Bv = xdbl[r2*NDBL + DTRANK + n];
      Cv = xdbl[r2*NDBL + DTRANK + NSTATE + n];
    }
    const float dA = expf(dlc*a);
    h = dA*h + dlc*Bvc*xvc;
    float p = h*Cvc;
    p += __shfl_xor(p,1,16);
    p += __shfl_xor(p,2,16);
    p += __shfl_xor(p,4,16);
    p += __shfl_xor(p,8,16);
    if (n==0){
      const size_t o = (rb+t)*DINNER + d;
      const float zv = zy[o];
      float y = p + xvc*Dv;
      y *= zv/(1.f+expf(-zv));
      zy[o] = y;
    }
  }
}

extern "C" void kernel_launch(void* const* d_in, const int* in_sizes, int n_in,
                              void* d_out, int out_size, void* d_ws, size_t ws_size,
                              hipStream_t stream){
  (void)in_sizes; (void)n_in; (void)out_size; (void)ws_size;
  const float* hidden    = (const float*)d_in[0];
  const float* rms_w     = (const float*)d_in[1];
  const float* in_proj_w = (const float*)d_in[2];
  const float* x_proj_w  = (const float*)d_in[3];
  const float* out_proj_w= (const float*)d_in[4];
  const float* conv_w    = (const float*)d_in[5];
  const float* conv_b    = (const float*)d_in[6];
  const float* dt_proj_w = (const float*)d_in[7];
  const float* dt_proj_b = (const float*)d_in[8];
  const float* A_log     = (const float*)d_in[9];
  const float* Dp        = (const float*)d_in[10];

  char* ws = (char*)d_ws; size_t off = 0;
  auto alloc = [&](size_t b)->void* { void* p = ws + off; off += (b + 255) & ~(size_t)255; return p; };
  float* part0 = (float*)alloc(512*4);
  float* part1 = (float*)alloc(512*4);
  float* part2 = (float*)alloc(512*4);
  float* wsc   = (float*)alloc(256);
  float* RS    = (float*)alloc((size_t)ROWS*4);
  __hip_bfloat16* WQin  = (__hip_bfloat16*)alloc((size_t)4096*1024*2);
  __hip_bfloat16* WQx   = (__hip_bfloat16*)alloc((size_t)128*2048*2);
  __hip_bfloat16* WQout = (__hip_bfloat16*)alloc((size_t)1024*2048*2);
  __hip_bfloat16* QA    = (__hip_bfloat16*)alloc((size_t)ROWS*2048*2);
  float* XBUF  = (float*)alloc((size_t)ROWS*DINNER*4);   // pre-conv x; later reused as delta
  float* ZBUF  = (float*)alloc((size_t)ROWS*DINNER*4);   // z; y written in place
  float* XC    = (float*)alloc((size_t)ROWS*DINNER*4);   // post conv+silu x
  float* XDBL  = (float*)alloc((size_t)ROWS*NDBL*4);

  // zero padded region of WQx (rows 96..127)
  hipMemsetAsync(WQx, 0, (size_t)128*2048*2, stream);

  // weight ternarization
  const int n_in_w  = 4096*1024;
  const int n_x_w   = NDBL*DINNER;
  const int n_out_w = 1024*2048;
  absmean_partial_k<<<512,256,0,stream>>>(in_proj_w,  n_in_w,  part0);
  absmean_final_k<<<1,256,0,stream>>>(part0, (float)n_in_w,  wsc+0);
  ternarize_k<<<(n_in_w+255)/256,256,0,stream>>>(in_proj_w, WQin, n_in_w, wsc+0);
  absmean_partial_k<<<512,256,0,stream>>>(x_proj_w,   n_x_w,   part1);
  absmean_final_k<<<1,256,0,stream>>>(part1, (float)n_x_w,   wsc+1);
  ternarize_k<<<(n_x_w+255)/256,256,0,stream>>>(x_proj_w, WQx, n_x_w, wsc+1);
  absmean_partial_k<<<512,256,0,stream>>>(out_proj_w, n_out_w, part2);
  absmean_final_k<<<1,256,0,stream>>>(part2, (float)n_out_w, wsc+2);
  ternarize_k<<<(n_out_w+255)/256,256,0,stream>>>(out_proj_w, WQout, n_out_w, wsc+2);

  // 1) rms_norm + LN + act-quant of hidden
  ln_quant_k<4><<<ROWS,256,0,stream>>>(hidden, rms_w, QA, RS);
  // 2) in_proj GEMM -> x (XBUF), z (ZBUF)
  gemm_q_k<<<dim3(ROWS/128, 4096/128),256,0,stream>>>((const short*)QA,(const short*)WQin,
      RS, DIM, 4096, 1, 0, XBUF, ZBUF, nullptr);
  // 3) conv + silu
  conv_silu_k<<<(ROWS*DINNER)/256,256,0,stream>>>(XBUF, conv_w, conv_b, XC);
  // 4) LN + quant of conv output
  ln_quant_k<8><<<ROWS,256,0,stream>>>(XC, nullptr, QA, RS);
  // 5) x_proj GEMM -> XDBL [2048][96]
  gemm_q_k<<<dim3(ROWS/128, 1),256,0,stream>>>((const short*)QA,(const short*)WQx,
      RS, DINNER, NDBL, 0, NDBL, XDBL, nullptr, nullptr);
  // 6) dt_proj + softplus -> delta (reuses XBUF)
  dt_delta_k<<<dim3(ROWS/32, DINNER/64),256,0,stream>>>(XDBL, dt_proj_w, dt_proj_b, XBUF);
  // 7) selective scan; y over z in place
  scan_k<<<(BATCH*DINNER*NSTATE)/256,256,0,stream>>>(XBUF, XC, XDBL, A_log, Dp, ZBUF);
  // 8) LN + quant of y
  ln_quant_k<8><<<ROWS,256,0,stream>>>(ZBUF, nullptr, QA, RS);
  // 9) out_proj GEMM + residual -> d_out
  gemm_q_k<<<dim3(ROWS/128, 1024/128),256,0,stream>>>((const short*)QA,(const short*)WQout,
      RS, DINNER, DIM, 2, DIM, (float*)d_out, nullptr, hidden);
}

// Round 2
// 309.891 us; speedup vs baseline: 2.8272x; 2.8272x over previous
//
#include <hip/hip_runtime.h>
#include <hip/hip_bf16.h>

#define BATCH 2
#define SEQ 1024
#define DIM 1024
#define DINNER 2048
#define NSTATE 16
#define DTRANK 64
#define NDBL 96
#define ROWS (BATCH*SEQ)
#define NC 32
#define TC 32

typedef __attribute__((ext_vector_type(8))) short bf16x8;
typedef __attribute__((ext_vector_type(4))) float f32x4;

__device__ inline float wave_sum64(float v){
#pragma unroll
  for (int o=32;o>0;o>>=1) v += __shfl_xor(v,o,64);
  return v;
}
__device__ inline float wave_max64(float v){
#pragma unroll
  for (int o=32;o>0;o>>=1) v = fmaxf(v,__shfl_xor(v,o,64));
  return v;
}
__device__ inline float block_sum256(float v, float* sred){
  v = wave_sum64(v);
  if ((threadIdx.x&63)==0) sred[threadIdx.x>>6]=v;
  __syncthreads();
  float t = sred[0]+sred[1]+sred[2]+sred[3];
  __syncthreads();
  return t;
}
__device__ inline float block_max256(float v, float* sred){
  v = wave_max64(v);
  if ((threadIdx.x&63)==0) sred[threadIdx.x>>6]=v;
  __syncthreads();
  float t = fmaxf(fmaxf(sred[0],sred[1]),fmaxf(sred[2],sred[3]));
  __syncthreads();
  return t;
}

// ---------- weight ternarization ----------
__global__ __launch_bounds__(256) void absmean_partial_k(const float* __restrict__ w, int n,
                                                         float* __restrict__ part){
  __shared__ float sred[4];
  float s = 0.f;
  for (int i = blockIdx.x*256 + threadIdx.x; i < n; i += 512*256) s += fabsf(w[i]);
  s = block_sum256(s, sred);
  if (threadIdx.x==0) part[blockIdx.x] = s;
}
__global__ __launch_bounds__(256) void absmean_final_k(const float* __restrict__ part,
                                                       float count, float* __restrict__ out){
  __shared__ float sred[4];
  float s = part[threadIdx.x] + part[threadIdx.x+256];
  s = block_sum256(s, sred);
  if (threadIdx.x==0) *out = fmaxf(s/count, 1e-5f);
}
__global__ __launch_bounds__(256) void ternarize_k(const float* __restrict__ w,
                                                   __hip_bfloat16* __restrict__ wq, int n,
                                                   const float* __restrict__ scale){
  int i = blockIdx.x*256 + threadIdx.x;
  if (i<n){
    float q = rintf(w[i] / *scale);
    q = fminf(fmaxf(q,-1.f),1.f);
    wq[i] = __float2bfloat16(q);
  }
}

// ---------- fused (optional rms_norm) + LayerNorm + activation int8 fake-quant ----------
template<int NV>
__global__ __launch_bounds__(256) void ln_quant_k(const float* __restrict__ src,
    const float* __restrict__ rmsw, __hip_bfloat16* __restrict__ q, float* __restrict__ rs){
  constexpr int C = NV*256;
  __shared__ float sred[4];
  const int r = blockIdx.x, tid = threadIdx.x;
  const float* row = src + (size_t)r*C;
  float v[NV];
#pragma unroll
  for (int i=0;i<NV;i++) v[i] = row[tid + i*256];
  if (rmsw){
    float ss=0.f;
#pragma unroll
    for (int i=0;i<NV;i++) ss += v[i]*v[i];
    ss = block_sum256(ss, sred);
    float f = rsqrtf(ss/(float)C + 1e-6f);
#pragma unroll
    for (int i=0;i<NV;i++) v[i] *= f * rmsw[tid + i*256];
  }
  float s=0.f;
#pragma unroll
  for (int i=0;i<NV;i++) s += v[i];
  s = block_sum256(s, sred);
  const float mu = s/(float)C;
  float vs=0.f;
#pragma unroll
  for (int i=0;i<NV;i++){ float d=v[i]-mu; vs += d*d; }
  vs = block_sum256(vs, sred);
  const float inv = rsqrtf(vs/(float)C + 1e-5f);
  float am=0.f;
#pragma unroll
  for (int i=0;i<NV;i++){ v[i] = (v[i]-mu)*inv; am = fmaxf(am, fabsf(v[i])); }
  am = block_max256(am, sred);
  am = fmaxf(am, 1e-5f);
  const float scale = 127.f/am;
  if (tid==0) rs[r] = am*(1.f/127.f);
#pragma unroll
  for (int i=0;i<NV;i++){
    float qv = fminf(fmaxf(rintf(v[i]*scale), -128.f), 127.f);
    q[(size_t)r*C + tid + i*256] = __float2bfloat16(qv);
  }
}

// ---------- bf16 MFMA GEMM: C[M,N] = rs[m] * sum_k A[m,k]*B[n,k] ----------
__global__ __launch_bounds__(256) void gemm_q_k(
    const short* __restrict__ A, const short* __restrict__ Bw,
    const float* __restrict__ rs, int K, int Nact, int mode, int ldc,
    float* __restrict__ out0, float* __restrict__ out1,
    const float* __restrict__ hid)
{
  __shared__ short lsA[128*32];
  __shared__ short lsB[128*32];
  const int tid = threadIdx.x;
  const int w = tid>>6, l = tid&63;
  const int m0 = blockIdx.x*128, n0 = blockIdx.y*128;
  const int wr = (w>>1)*64, wc = (w&1)*64;
  f32x4 acc[4][4];
#pragma unroll
  for (int m=0;m<4;m++)
#pragma unroll
    for (int n=0;n<4;n++) acc[m][n] = (f32x4){0.f,0.f,0.f,0.f};

  const size_t KB = (size_t)K*2;
  const char* Ag = (const char*)A + (size_t)m0*KB;
  const char* Bg = (const char*)Bw + (size_t)n0*KB;
  const int lr = l&15, lk = (l>>4)*16;

  for (int kk=0; kk<K; kk+=32){
    __syncthreads();
#pragma unroll
    for (int c0=0;c0<2;c0++){
      int c = tid + c0*256;
      int o = c<<4;
      int rrow = o>>6, x = o&63;
      bf16x8 va = *(const bf16x8*)(Ag + (size_t)rrow*KB + (size_t)kk*2 + x);
      bf16x8 vb = *(const bf16x8*)(Bg + (size_t)rrow*KB + (size_t)kk*2 + x);
      *(bf16x8*)((char*)lsA + o) = va;
      *(bf16x8*)((char*)lsB + o) = vb;
    }
    __syncthreads();
    bf16x8 af[4], bb[4];
#pragma unroll
    for (int m=0;m<4;m++) af[m] = *(const bf16x8*)((const char*)lsA + (size_t)(wr + m*16 + lr)*64 + lk);
#pragma unroll
    for (int n=0;n<4;n++) bb[n] = *(const bf16x8*)((const char*)lsB + (size_t)(wc + n*16 + lr)*64 + lk);
#pragma unroll
    for (int m=0;m<4;m++)
#pragma unroll
      for (int n=0;n<4;n++)
        acc[m][n] = __builtin_amdgcn_mfma_f32_16x16x32_bf16(af[m], bb[n], acc[m][n], 0, 0, 0);
  }

  const int lg = l>>4;
#pragma unroll
  for (int m=0;m<4;m++){
    const int rowb = m0 + wr + m*16 + lg*4;
#pragma unroll
    for (int j=0;j<4;j++){
      const int row = rowb + j;
      const float rsv = rs[row];
#pragma unroll
      for (int n=0;n<4;n++){
        const int col = n0 + wc + n*16 + lr;
        const float v = acc[m][n][j]*rsv;
        if (mode==1){
          if (col < 2048) out0[(size_t)row*2048 + col] = v;
          else            out1[(size_t)row*2048 + (col-2048)] = v;
        } else if (mode==2){
          const size_t o = (size_t)row*ldc + col;
          out0[o] = hid[o] + v;
        } else {
          if (col < Nact) out0[(size_t)row*ldc + col] = v;
        }
      }
    }
  }
}

// ---------- depthwise causal conv1d (k=4) + bias + silu ----------
__global__ __launch_bounds__(256) void conv_silu_k(const float* __restrict__ x,
    const float* __restrict__ cw, const float* __restrict__ cb, float* __restrict__ xc){
  const int idx = blockIdx.x*256 + threadIdx.x;
  const int d = idx & (DINNER-1);
  const int t = (idx>>11) & (SEQ-1);
  const int b = idx>>21;
  const float* wd = cw + (size_t)d*4;
  float acc = cb[d];
#pragma unroll
  for (int j=0;j<4;j++){
    const int tt = t-3+j;
    if (tt>=0) acc += x[((size_t)(b*SEQ+tt))*DINNER + d]*wd[j];
  }
  xc[(size_t)idx] = acc/(1.f+expf(-acc));
}

// ---------- dt = xdbl[:, :64] @ W^T + 2b ; delta = softplus(dt) ----------
__global__ __launch_bounds__(256) void dt_delta_k(const float* __restrict__ xdbl,
    const float* __restrict__ W, const float* __restrict__ bias, float* __restrict__ delta){
  __shared__ float sW[64][65];
  __shared__ float sX[32][64];
  const int tid = threadIdx.x;
  const int r0 = blockIdx.x*32, d0 = blockIdx.y*64;
  for (int i=tid;i<64*64;i+=256){ int rr=i>>6, cc=i&63; sW[rr][cc] = W[(size_t)(d0+rr)*64+cc]; }
  for (int i=tid;i<32*64;i+=256){ int rr=i>>6, cc=i&63; sX[rr][cc] = xdbl[(size_t)(r0+rr)*NDBL+cc]; }
  __syncthreads();
  const int dl = tid&63, ty = tid>>6;
  const float b2 = 2.f*bias[d0+dl];
  float acc[8];
#pragma unroll
  for (int i=0;i<8;i++) acc[i]=0.f;
#pragma unroll 8
  for (int k=0;k<64;k++){
    const float wv = sW[dl][k];
#pragma unroll
    for (int i=0;i<8;i++) acc[i] += sX[ty*8+i][k]*wv;
  }
#pragma unroll
  for (int i=0;i<8;i++){
    const float xq = acc[i] + b2;
    const float sp = (xq>20.f) ? xq : log1pf(expf(xq));
    delta[(size_t)(r0+ty*8+i)*DINNER + d0+dl] = sp;
  }
}

// ---------- chunked selective scan ----------
// pass 1: per (b,d,chunk) thread: local scan from h=0 over TC steps.
// stores h_loc[16] and S=sum(delta).
__global__ __launch_bounds__(256) void scan1_k(const float* __restrict__ delta,
    const float* __restrict__ xc, const float* __restrict__ xdbl,
    const float* __restrict__ A_log, float* __restrict__ hloc, float* __restrict__ Ssum){
  __shared__ float sB[TC][16];
  const int tid = threadIdx.x;
  const int d = blockIdx.x*256 + tid;
  const int c = blockIdx.y, b = blockIdx.z;
  const int row0 = b*SEQ + c*TC;
  for (int i=tid;i<TC*16;i+=256){
    int t=i>>4, j=i&15;
    sB[t][j] = xdbl[(size_t)(row0+t)*NDBL + DTRANK + j];
  }
  __syncthreads();
  float a[16];
  const f32x4* Ap = (const f32x4*)(A_log + (size_t)d*16);
#pragma unroll
  for (int q=0;q<4;q++){
    f32x4 av = Ap[q];
#pragma unroll
    for (int j=0;j<4;j++) a[q*4+j] = -__expf(av[j]);
  }
  float h[16];
#pragma unroll
  for (int n=0;n<16;n++) h[n]=0.f;
  float S = 0.f;
  float dl = delta[(size_t)row0*DINNER + d];
  float xv = xc[(size_t)row0*DINNER + d];
  for (int t=0;t<TC;t++){
    const float dlc=dl, xvc=xv;
    if (t<TC-1){
      dl = delta[(size_t)(row0+t+1)*DINNER + d];
      xv = xc[(size_t)(row0+t+1)*DINNER + d];
    }
    S += dlc;
    const float dx = dlc*xvc;
#pragma unroll
    for (int n=0;n<16;n++)
      h[n] = fmaf(__expf(dlc*a[n]), h[n], dx*sB[t][n]);
  }
  f32x4* hp = (f32x4*)(hloc + ((size_t)(b*NC+c)*DINNER + d)*16);
#pragma unroll
  for (int q=0;q<4;q++){
    f32x4 hv;
#pragma unroll
    for (int j=0;j<4;j++) hv[j]=h[q*4+j];
    hp[q]=hv;
  }
  Ssum[(size_t)(b*NC+c)*DINNER + d] = S;
}

// pass 2: sequential over chunks; hloc -> h_in (in place)
__global__ __launch_bounds__(256) void scan2_k(const float* __restrict__ A_log,
    const float* __restrict__ Ssum, float* __restrict__ hloc){
  const int idx = blockIdx.x*256 + threadIdx.x;       // b*DINNER*16
  const int n = idx&15, d = (idx>>4)&(DINNER-1), b = idx>>15;
  const float a = -__expf(A_log[(size_t)d*16+n]);
  float hin = 0.f;
  for (int c=0;c<NC;c++){
    const size_t o = ((size_t)(b*NC+c)*DINNER + d)*16 + n;
    const float t = hloc[o];
    hloc[o] = hin;
    hin = fmaf(__expf(a*Ssum[(size_t)(b*NC+c)*DINNER + d]), hin, t);
  }
}

// pass 3: local scan seeded with h_in; emits y = (sum h*C + x*D) * silu(z)
__global__ __launch_bounds__(256) void scan3_k(const float* __restrict__ delta,
    const float* __restrict__ xc, const float* __restrict__ xdbl,
    const float* __restrict__ A_log, const float* __restrict__ Dp,
    const float* __restrict__ hloc, float* __restrict__ zy){
  __shared__ float sBC[TC][32];
  const int tid = threadIdx.x;
  const int d = blockIdx.x*256 + tid;
  const int c = blockIdx.y, b = blockIdx.z;
  const int row0 = b*SEQ + c*TC;
  for (int i=tid;i<TC*32;i+=256){
    int t=i>>5, j=i&31;
    sBC[t][j] = xdbl[(size_t)(row0+t)*NDBL + DTRANK + j];
  }
  __syncthreads();
  float a[16];
  const f32x4* Ap = (const f32x4*)(A_log + (size_t)d*16);
#pragma unroll
  for (int q=0;q<4;q++){
    f32x4 av = Ap[q];
#pragma unroll
    for (int j=0;j<4;j++) a[q*4+j] = -__expf(av[j]);
  }
  float h[16];
  const f32x4* hp = (const f32x4*)(hloc + ((size_t)(b*NC+c)*DINNER + d)*16);
#pragma unroll
  for (int q=0;q<4;q++){
    f32x4 hv = hp[q];
#pragma unroll
    for (int j=0;j<4;j++) h[q*4+j]=hv[j];
  }
  const float Dv = Dp[d];
  float dl = delta[(size_t)row0*DINNER + d];
  float xv = xc[(size_t)row0*DINNER + d];
  float zv = zy[(size_t)row0*DINNER + d];
  for (int t=0;t<TC;t++){
    const float dlc=dl, xvc=xv, zvc=zv;
    if (t<TC-1){
      dl = delta[(size_t)(row0+t+1)*DINNER + d];
      xv = xc[(size_t)(row0+t+1)*DINNER + d];
      zv = zy[(size_t)(row0+t+1)*DINNER + d];
    }
    const float dx = dlc*xvc;
    float p = 0.f;
#pragma unroll
    for (int n=0;n<16;n++){
      h[n] = fmaf(__expf(dlc*a[n]), h[n], dx*sBC[t][n]);
      p = fmaf(h[n], sBC[t][16+n], p);
    }
    float y = p + xvc*Dv;
    y *= zvc/(1.f+__expf(-zvc));
    zy[(size_t)(row0+t)*DINNER + d] = y;
  }
}

extern "C" void kernel_launch(void* const* d_in, const int* in_sizes, int n_in,
                              void* d_out, int out_size, void* d_ws, size_t ws_size,
                              hipStream_t stream){
  (void)in_sizes; (void)n_in; (void)out_size; (void)ws_size;
  const float* hidden    = (const float*)d_in[0];
  const float* rms_w     = (const float*)d_in[1];
  const float* in_proj_w = (const float*)d_in[2];
  const float* x_proj_w  = (const float*)d_in[3];
  const float* out_proj_w= (const float*)d_in[4];
  const float* conv_w    = (const float*)d_in[5];
  const float* conv_b    = (const float*)d_in[6];
  const float* dt_proj_w = (const float*)d_in[7];
  const float* dt_proj_b = (const float*)d_in[8];
  const float* A_log     = (const float*)d_in[9];
  const float* Dp        = (const float*)d_in[10];

  char* ws = (char*)d_ws; size_t off = 0;
  auto alloc = [&](size_t b)->void* { void* p = ws + off; off += (b + 255) & ~(size_t)255; return p; };
  float* part0 = (float*)alloc(512*4);
  float* part1 = (float*)alloc(512*4);
  float* part2 = (float*)alloc(512*4);
  float* wsc   = (float*)alloc(256);
  float* RS    = (float*)alloc((size_t)ROWS*4);
  __hip_bfloat16* WQin  = (__hip_bfloat16*)alloc((size_t)4096*1024*2);
  __hip_bfloat16* WQx   = (__hip_bfloat16*)alloc((size_t)128*2048*2);
  __hip_bfloat16* WQout = (__hip_bfloat16*)alloc((size_t)1024*2048*2);
  __hip_bfloat16* QA    = (__hip_bfloat16*)alloc((size_t)ROWS*2048*2);
  float* XBUF  = (float*)alloc((size_t)ROWS*DINNER*4);   // pre-conv x; later reused as delta
  float* ZBUF  = (float*)alloc((size_t)ROWS*DINNER*4);   // z; y written in place
  float* XC    = (float*)alloc((size_t)ROWS*DINNER*4);   // post conv+silu x
  float* XDBL  = (float*)alloc((size_t)ROWS*NDBL*4);
  float* HLOC  = (float*)alloc((size_t)BATCH*NC*DINNER*16*4);
  float* SSUM  = (float*)alloc((size_t)BATCH*NC*DINNER*4);

  hipMemsetAsync(WQx, 0, (size_t)128*2048*2, stream);

  const int n_in_w  = 4096*1024;
  const int n_x_w   = NDBL*DINNER;
  const int n_out_w = 1024*2048;
  absmean_partial_k<<<512,256,0,stream>>>(in_proj_w,  n_in_w,  part0);
  absmean_final_k<<<1,256,0,stream>>>(part0, (float)n_in_w,  wsc+0);
  ternarize_k<<<(n_in_w+255)/256,256,0,stream>>>(in_proj_w, WQin, n_in_w, wsc+0);
  absmean_partial_k<<<512,256,0,stream>>>(x_proj_w,   n_x_w,   part1);
  absmean_final_k<<<1,256,0,stream>>>(part1, (float)n_x_w,   wsc+1);
  ternarize_k<<<(n_x_w+255)/256,256,0,stream>>>(x_proj_w, WQx, n_x_w, wsc+1);
  absmean_partial_k<<<512,256,0,stream>>>(out_proj_w, n_out_w, part2);
  absmean_final_k<<<1,256,0,stream>>>(part2, (float)n_out_w, wsc+2);
  ternarize_k<<<(n_out_w+255)/256,256,0,stream>>>(out_proj_w, WQout, n_out_w, wsc+2);

  // 1) rms_norm + LN + act-quant of hidden
  ln_quant_k<4><<<ROWS,256,0,stream>>>(hidden, rms_w, QA, RS);
  // 2) in_proj GEMM -> x (XBUF), z (ZBUF)
  gemm_q_k<<<dim3(ROWS/128, 4096/128),256,0,stream>>>((const short*)QA,(const short*)WQin,
      RS, DIM, 4096, 1, 0, XBUF, ZBUF, nullptr);
  // 3) conv + silu
  conv_silu_k<<<(ROWS*DINNER)/256,256,0,stream>>>(XBUF, conv_w, conv_b, XC);
  // 4) LN + quant of conv output
  ln_quant_k<8><<<ROWS,256,0,stream>>>(XC, nullptr, QA, RS);
  // 5) x_proj GEMM -> XDBL [2048][96]
  gemm_q_k<<<dim3(ROWS/128, 1),256,0,stream>>>((const short*)QA,(const short*)WQx,
      RS, DINNER, NDBL, 0, NDBL, XDBL, nullptr, nullptr);
  // 6) dt_proj + softplus -> delta (reuses XBUF)
  dt_delta_k<<<dim3(ROWS/32, DINNER/64),256,0,stream>>>(XDBL, dt_proj_w, dt_proj_b, XBUF);
  // 7) chunked selective scan; y over z in place
  scan1_k<<<dim3(DINNER/256, NC, BATCH),256,0,stream>>>(XBUF, XC, XDBL, A_log, HLOC, SSUM);
  scan2_k<<<(BATCH*DINNER*16)/256,256,0,stream>>>(A_log, SSUM, HLOC);
  scan3_k<<<dim3(DINNER/256, NC, BATCH),256,0,stream>>>(XBUF, XC, XDBL, A_log, Dp, HLOC, ZBUF);
  // 8) LN + quant of y
  ln_quant_k<8><<<ROWS,256,0,stream>>>(ZBUF, nullptr, QA, RS);
  // 9) out_proj GEMM + residual -> d_out
  gemm_q_k<<<dim3(ROWS/128, 1024/128),256,0,stream>>>((const short*)QA,(const short*)WQout,
      RS, DINNER, DIM, 2, DIM, (float*)d_out, nullptr, hidden);
}

// Round 3
// 217.113 us; speedup vs baseline: 4.0353x; 1.4273x over previous
//
#include <hip/hip_runtime.h>
#include <hip/hip_bf16.h>

#define BATCH 2
#define SEQ 1024
#define DIM 1024
#define DINNER 2048
#define NSTATE 16
#define DTRANK 64
#define NDBL 96
#define ROWS (BATCH*SEQ)
#define NC 32
#define TC 32
#define KSPLIT 8

typedef __attribute__((ext_vector_type(8))) short bf16x8;
typedef __attribute__((ext_vector_type(4))) float f32x4;

__device__ inline float wave_sum64(float v){
#pragma unroll
  for (int o=32;o>0;o>>=1) v += __shfl_xor(v,o,64);
  return v;
}
__device__ inline float wave_max64(float v){
#pragma unroll
  for (int o=32;o>0;o>>=1) v = fmaxf(v,__shfl_xor(v,o,64));
  return v;
}
__device__ inline float block_sum256(float v, float* sred){
  v = wave_sum64(v);
  if ((threadIdx.x&63)==0) sred[threadIdx.x>>6]=v;
  __syncthreads();
  float t = sred[0]+sred[1]+sred[2]+sred[3];
  __syncthreads();
  return t;
}
__device__ inline float block_max256(float v, float* sred){
  v = wave_max64(v);
  if ((threadIdx.x&63)==0) sred[threadIdx.x>>6]=v;
  __syncthreads();
  float t = fmaxf(fmaxf(sred[0],sred[1]),fmaxf(sred[2],sred[3]));
  __syncthreads();
  return t;
}

// ---------- weight ternarization ----------
__global__ __launch_bounds__(256) void absmean_partial_k(const float* __restrict__ w, int n,
                                                         float* __restrict__ part){
  __shared__ float sred[4];
  float s = 0.f;
  for (int i = blockIdx.x*256 + threadIdx.x; i < n; i += 512*256) s += fabsf(w[i]);
  s = block_sum256(s, sred);
  if (threadIdx.x==0) part[blockIdx.x] = s;
}
__global__ __launch_bounds__(256) void absmean_final_k(const float* __restrict__ part,
                                                       float count, float* __restrict__ out){
  __shared__ float sred[4];
  float s = part[threadIdx.x] + part[threadIdx.x+256];
  s = block_sum256(s, sred);
  if (threadIdx.x==0) *out = fmaxf(s/count, 1e-5f);
}
__global__ __launch_bounds__(256) void ternarize4_k(const float* __restrict__ w,
                                                    ushort* __restrict__ wq, int n4,
                                                    const float* __restrict__ scale){
  int i = blockIdx.x*256 + threadIdx.x;
  if (i<n4){
    const float s = *scale;
    const float4 v = ((const float4*)w)[i];
    float q0 = fminf(fmaxf(rintf(v.x/s),-1.f),1.f);
    float q1 = fminf(fmaxf(rintf(v.y/s),-1.f),1.f);
    float q2 = fminf(fmaxf(rintf(v.z/s),-1.f),1.f);
    float q3 = fminf(fmaxf(rintf(v.w/s),-1.f),1.f);
    __hip_bfloat16 h0=__float2bfloat16(q0), h1=__float2bfloat16(q1);
    __hip_bfloat16 h2=__float2bfloat16(q2), h3=__float2bfloat16(q3);
    ushort4 o;
    o.x=*(ushort*)&h0; o.y=*(ushort*)&h1; o.z=*(ushort*)&h2; o.w=*(ushort*)&h3;
    ((ushort4*)wq)[i]=o;
  }
}

// ---------- fused (optional rms_norm) + LayerNorm + activation int8 fake-quant ----------
template<int NV>
__global__ __launch_bounds__(256) void ln_quant_k(const float* __restrict__ src,
    const float* __restrict__ rmsw, __hip_bfloat16* __restrict__ q, float* __restrict__ rs){
  constexpr int C = NV*256;
  __shared__ float sred[4];
  const int r = blockIdx.x, tid = threadIdx.x;
  const float* row = src + (size_t)r*C;
  float v[NV];
#pragma unroll
  for (int i=0;i<NV;i++) v[i] = row[tid + i*256];
  if (rmsw){
    float ss=0.f;
#pragma unroll
    for (int i=0;i<NV;i++) ss += v[i]*v[i];
    ss = block_sum256(ss, sred);
    float f = rsqrtf(ss/(float)C + 1e-6f);
#pragma unroll
    for (int i=0;i<NV;i++) v[i] *= f * rmsw[tid + i*256];
  }
  float s=0.f;
#pragma unroll
  for (int i=0;i<NV;i++) s += v[i];
  s = block_sum256(s, sred);
  const float mu = s/(float)C;
  float vs=0.f;
#pragma unroll
  for (int i=0;i<NV;i++){ float d=v[i]-mu; vs += d*d; }
  vs = block_sum256(vs, sred);
  const float inv = rsqrtf(vs/(float)C + 1e-5f);
  float am=0.f;
#pragma unroll
  for (int i=0;i<NV;i++){ v[i] = (v[i]-mu)*inv; am = fmaxf(am, fabsf(v[i])); }
  am = block_max256(am, sred);
  am = fmaxf(am, 1e-5f);
  const float scale = 127.f/am;
  if (tid==0) rs[r] = am*(1.f/127.f);
#pragma unroll
  for (int i=0;i<NV;i++){
    float qv = fminf(fmaxf(rintf(v[i]*scale), -128.f), 127.f);
    q[(size_t)r*C + tid + i*256] = __float2bfloat16(qv);
  }
}

// ---------- bf16 MFMA GEMM, BK=64, swizzled LDS ----------
// MODE 1: split cols: <2048 -> out0, else -> out1 (both ld 2048), scaled by rs
// MODE 2: out0[row*ldc+col] = hid[...] + rs*acc
// MODE 3: raw partial: out0[(blockIdx.z*2048+row)*128+col] = acc (no rs)
template<int BM, int BN, int MODE>
__global__ __launch_bounds__(256) void gemm2_k(
    const short* __restrict__ A, const short* __restrict__ Bw,
    const float* __restrict__ rs, int K, int Ksub, int ldc,
    float* __restrict__ out0, float* __restrict__ out1,
    const float* __restrict__ hid)
{
  constexpr int MF = BM/32;      // m-frags per wave
  constexpr int NF = BN/32;      // n-frags per wave
  constexpr int CA = BM/32;      // A stage chunks of 4KB
  constexpr int CB = BN/32;      // B stage chunks of 4KB
  __shared__ short lsA[BM*64];
  __shared__ short lsB[BN*64];
  const int tid = threadIdx.x;
  const int w = tid>>6, l = tid&63;
  const int m0 = blockIdx.x*BM, n0 = blockIdx.y*BN;
  const int wr = (w>>1)*(BM/2), wc = (w&1)*(BN/2);
  const int lr = l&15, g = l>>4;
  f32x4 acc[MF][NF];
#pragma unroll
  for (int m=0;m<MF;m++)
#pragma unroll
    for (int n=0;n<NF;n++) acc[m][n] = (f32x4){0.f,0.f,0.f,0.f};

  const size_t KB = (size_t)K*2;
  const char* Ag = (const char*)A + (size_t)m0*KB + (size_t)blockIdx.z*Ksub*2;
  const char* Bg = (const char*)Bw + (size_t)n0*KB + (size_t)blockIdx.z*Ksub*2;

  bf16x8 ra[CA], rb[CB];
#define LDG(kb)                                                                   \
  {                                                                               \
    _Pragma("unroll")                                                             \
    for (int c=0;c<CA;c++){ int o=c*4096+tid*16; int rw=o>>7, cl=o&127;           \
      ra[c] = *(const bf16x8*)(Ag + (size_t)rw*KB + (size_t)(kb)*2 + cl); }       \
    _Pragma("unroll")                                                             \
    for (int c=0;c<CB;c++){ int o=c*4096+tid*16; int rw=o>>7, cl=o&127;           \
      rb[c] = *(const bf16x8*)(Bg + (size_t)rw*KB + (size_t)(kb)*2 + cl); }       \
  }

  LDG(0);
  for (int kb=0; kb<Ksub; kb+=64){
    __syncthreads();
#pragma unroll
    for (int c=0;c<CA;c++){ int o=c*4096+tid*16; int rw=o>>7, sl=(o>>4)&7;
      *(bf16x8*)((char*)lsA + (rw<<7) + ((sl^(rw&7))<<4)) = ra[c]; }
#pragma unroll
    for (int c=0;c<CB;c++){ int o=c*4096+tid*16; int rw=o>>7, sl=(o>>4)&7;
      *(bf16x8*)((char*)lsB + (rw<<7) + ((sl^(rw&7))<<4)) = rb[c]; }
    __syncthreads();
    if (kb + 64 < Ksub) LDG(kb+64);
#pragma unroll
    for (int ks=0;ks<2;ks++){
      bf16x8 af[MF], bb[NF];
#pragma unroll
      for (int m=0;m<MF;m++){ int rw = wr + m*16 + lr;
        af[m] = *(const bf16x8*)((const char*)lsA + (rw<<7) + ((((ks<<2)+g)^(lr&7))<<4)); }
#pragma unroll
      for (int n=0;n<NF;n++){ int rw = wc + n*16 + lr;
        bb[n] = *(const bf16x8*)((const char*)lsB + (rw<<7) + ((((ks<<2)+g)^(lr&7))<<4)); }
#pragma unroll
      for (int m=0;m<MF;m++)
#pragma unroll
        for (int n=0;n<NF;n++)
          acc[m][n] = __builtin_amdgcn_mfma_f32_16x16x32_bf16(af[m], bb[n], acc[m][n], 0, 0, 0);
    }
  }
#undef LDG

#pragma unroll
  for (int m=0;m<MF;m++){
    const int rowb = m0 + wr + m*16 + g*4;
#pragma unroll
    for (int j=0;j<4;j++){
      const int row = rowb + j;
      const float rsv = (MODE==3) ? 1.f : rs[row];
#pragma unroll
      for (int n=0;n<NF;n++){
        const int col = n0 + wc + n*16 + lr;
        const float v = acc[m][n][j]*rsv;
        if (MODE==1){
          if (col < 2048) out0[(size_t)row*2048 + col] = v;
          else            out1[(size_t)row*2048 + (col-2048)] = v;
        } else if (MODE==2){
          const size_t o = (size_t)row*ldc + col;
          out0[o] = hid[o] + v;
        } else {
          out0[((size_t)blockIdx.z*2048 + row)*128 + col] = v;
        }
      }
    }
  }
}

// combine split-K partials for x_proj (exact integer sums -> bitwise stable)
__global__ __launch_bounds__(256) void xproj_combine_k(const float* __restrict__ part,
    const float* __restrict__ rs, float* __restrict__ xdbl){
  const int idx = blockIdx.x*256 + threadIdx.x;       // ROWS*NDBL
  const int row = idx/NDBL, c = idx - row*NDBL;
  float s = 0.f;
#pragma unroll
  for (int z=0; z<KSPLIT; z++) s += part[((size_t)z*ROWS + row)*128 + c];
  xdbl[(size_t)idx] = s * rs[row];
}

// ---------- depthwise causal conv1d (k=4) + bias + silu ----------
__global__ __launch_bounds__(256) void conv_silu_k(const float* __restrict__ x,
    const float* __restrict__ cw, const float* __restrict__ cb, float* __restrict__ xc){
  const int idx = blockIdx.x*256 + threadIdx.x;
  const int d = idx & (DINNER-1);
  const int t = (idx>>11) & (SEQ-1);
  const int b = idx>>21;
  const float* wd = cw + (size_t)d*4;
  float acc = cb[d];
#pragma unroll
  for (int j=0;j<4;j++){
    const int tt = t-3+j;
    if (tt>=0) acc += x[((size_t)(b*SEQ+tt))*DINNER + d]*wd[j];
  }
  xc[(size_t)idx] = acc/(1.f+expf(-acc));
}

// ---------- dt = xdbl[:, :64] @ W^T + 2b ; delta = softplus(dt) ----------
__global__ __launch_bounds__(256) void dt_delta_k(const float* __restrict__ xdbl,
    const float* __restrict__ W, const float* __restrict__ bias, float* __restrict__ delta){
  __shared__ float sW[64][65];
  __shared__ float sX[32][64];
  const int tid = threadIdx.x;
  const int r0 = blockIdx.x*32, d0 = blockIdx.y*64;
  for (int i=tid;i<64*64;i+=256){ int rr=i>>6, cc=i&63; sW[rr][cc] = W[(size_t)(d0+rr)*64+cc]; }
  for (int i=tid;i<32*64;i+=256){ int rr=i>>6, cc=i&63; sX[rr][cc] = xdbl[(size_t)(r0+rr)*NDBL+cc]; }
  __syncthreads();
  const int dl = tid&63, ty = tid>>6;
  const float b2 = 2.f*bias[d0+dl];
  float acc[8];
#pragma unroll
  for (int i=0;i<8;i++) acc[i]=0.f;
#pragma unroll 8
  for (int k=0;k<64;k++){
    const float wv = sW[dl][k];
#pragma unroll
    for (int i=0;i<8;i++) acc[i] += sX[ty*8+i][k]*wv;
  }
#pragma unroll
  for (int i=0;i<8;i++){
    const float xq = acc[i] + b2;
    const float sp = (xq>20.f) ? xq : log1pf(expf(xq));
    delta[(size_t)(r0+ty*8+i)*DINNER + d0+dl] = sp;
  }
}

// ---------- chunked selective scan ----------
__global__ __launch_bounds__(256) void scan1_k(const float* __restrict__ delta,
    const float* __restrict__ xc, const float* __restrict__ xdbl,
    const float* __restrict__ A_log, float* __restrict__ hloc, float* __restrict__ Ssum){
  __shared__ float sB[TC][16];
  const int tid = threadIdx.x;
  const int d = blockIdx.x*256 + tid;
  const int c = blockIdx.y, b = blockIdx.z;
  const int row0 = b*SEQ + c*TC;
  for (int i=tid;i<TC*16;i+=256){
    int t=i>>4, j=i&15;
    sB[t][j] = xdbl[(size_t)(row0+t)*NDBL + DTRANK + j];
  }
  __syncthreads();
  float a[16];
  const f32x4* Ap = (const f32x4*)(A_log + (size_t)d*16);
#pragma unroll
  for (int q=0;q<4;q++){
    f32x4 av = Ap[q];
#pragma unroll
    for (int j=0;j<4;j++) a[q*4+j] = -__expf(av[j]);
  }
  float h[16];
#pragma unroll
  for (int n=0;n<16;n++) h[n]=0.f;
  float S = 0.f;
  float dl = delta[(size_t)row0*DINNER + d];
  float xv = xc[(size_t)row0*DINNER + d];
  for (int t=0;t<TC;t++){
    const float dlc=dl, xvc=xv;
    if (t<TC-1){
      dl = delta[(size_t)(row0+t+1)*DINNER + d];
      xv = xc[(size_t)(row0+t+1)*DINNER + d];
    }
    S += dlc;
    const float dx = dlc*xvc;
#pragma unroll
    for (int n=0;n<16;n++)
      h[n] = fmaf(__expf(dlc*a[n]), h[n], dx*sB[t][n]);
  }
  f32x4* hp = (f32x4*)(hloc + ((size_t)(b*NC+c)*DINNER + d)*16);
#pragma unroll
  for (int q=0;q<4;q++){
    f32x4 hv;
#pragma unroll
    for (int j=0;j<4;j++) hv[j]=h[q*4+j];
    hp[q]=hv;
  }
  Ssum[(size_t)(b*NC+c)*DINNER + d] = S;
}

__global__ __launch_bounds__(256) void scan2_k(const float* __restrict__ A_log,
    const float* __restrict__ Ssum, float* __restrict__ hloc){
  const int idx = blockIdx.x*256 + threadIdx.x;       // b*DINNER*16
  const int n = idx&15, d = (idx>>4)&(DINNER-1), b = idx>>15;
  const float a = -__expf(A_log[(size_t)d*16+n]);
  float hin = 0.f;
  for (int c=0;c<NC;c++){
    const size_t o = ((size_t)(b*NC+c)*DINNER + d)*16 + n;
    const float t = hloc[o];
    hloc[o] = hin;
    hin = fmaf(__expf(a*Ssum[(size_t)(b*NC+c)*DINNER + d]), hin, t);
  }
}

__global__ __launch_bounds__(256) void scan3_k(const float* __restrict__ delta,
    const float* __restrict__ xc, const float* __restrict__ xdbl,
    const float* __restrict__ A_log, const float* __restrict__ Dp,
    const float* __restrict__ hloc, float* __restrict__ zy){
  __shared__ float sBC[TC][32];
  const int tid = threadIdx.x;
  const int d = blockIdx.x*256 + tid;
  const int c = blockIdx.y, b = blockIdx.z;
  const int row0 = b*SEQ + c*TC;
  for (int i=tid;i<TC*32;i+=256){
    int t=i>>5, j=i&31;
    sBC[t][j] = xdbl[(size_t)(row0+t)*NDBL + DTRANK + j];
  }
  __syncthreads();
  float a[16];
  const f32x4* Ap = (const f32x4*)(A_log + (size_t)d*16);
#pragma unroll
  for (int q=0;q<4;q++){
    f32x4 av = Ap[q];
#pragma unroll
    for (int j=0;j<4;j++) a[q*4+j] = -__expf(av[j]);
  }
  float h[16];
  const f32x4* hp = (const f32x4*)(hloc + ((size_t)(b*NC+c)*DINNER + d)*16);
#pragma unroll
  for (int q=0;q<4;q++){
    f32x4 hv = hp[q];
#pragma unroll
    for (int j=0;j<4;j++) h[q*4+j]=hv[j];
  }
  const float Dv = Dp[d];
  float dl = delta[(size_t)row0*DINNER + d];
  float xv = xc[(size_t)row0*DINNER + d];
  float zv = zy[(size_t)row0*DINNER + d];
  for (int t=0;t<TC;t++){
    const float dlc=dl, xvc=xv, zvc=zv;
    if (t<TC-1){
      dl = delta[(size_t)(row0+t+1)*DINNER + d];
      xv = xc[(size_t)(row0+t+1)*DINNER + d];
      zv = zy[(size_t)(row0+t+1)*DINNER + d];
    }
    const float dx = dlc*xvc;
    float p = 0.f;
#pragma unroll
    for (int n=0;n<16;n++){
      h[n] = fmaf(__expf(dlc*a[n]), h[n], dx*sBC[t][n]);
      p = fmaf(h[n], sBC[t][16+n], p);
    }
    float y = p + xvc*Dv;
    y *= zvc/(1.f+__expf(-zvc));
    zy[(size_t)(row0+t)*DINNER + d] = y;
  }
}

extern "C" void kernel_launch(void* const* d_in, const int* in_sizes, int n_in,
                              void* d_out, int out_size, void* d_ws, size_t ws_size,
                              hipStream_t stream){
  (void)in_sizes; (void)n_in; (void)out_size; (void)ws_size;
  const float* hidden    = (const float*)d_in[0];
  const float* rms_w     = (const float*)d_in[1];
  const float* in_proj_w = (const float*)d_in[2];
  const float* x_proj_w  = (const float*)d_in[3];
  const float* out_proj_w= (const float*)d_in[4];
  const float* conv_w    = (const float*)d_in[5];
  const float* conv_b    = (const float*)d_in[6];
  const float* dt_proj_w = (const float*)d_in[7];
  const float* dt_proj_b = (const float*)d_in[8];
  const float* A_log     = (const float*)d_in[9];
  const float* Dp        = (const float*)d_in[10];

  char* ws = (char*)d_ws; size_t off = 0;
  auto alloc = [&](size_t b)->void* { void* p = ws + off; off += (b + 255) & ~(size_t)255; return p; };
  float* part0 = (float*)alloc(512*4);
  float* part1 = (float*)alloc(512*4);
  float* part2 = (float*)alloc(512*4);
  float* wsc   = (float*)alloc(256);
  float* RS    = (float*)alloc((size_t)ROWS*4);
  __hip_bfloat16* WQin  = (__hip_bfloat16*)alloc((size_t)4096*1024*2);
  __hip_bfloat16* WQx   = (__hip_bfloat16*)alloc((size_t)128*2048*2);
  __hip_bfloat16* WQout = (__hip_bfloat16*)alloc((size_t)1024*2048*2);
  __hip_bfloat16* QA    = (__hip_bfloat16*)alloc((size_t)ROWS*2048*2);
  float* XBUF  = (float*)alloc((size_t)ROWS*DINNER*4);   // pre-conv x; later reused as delta
  float* ZBUF  = (float*)alloc((size_t)ROWS*DINNER*4);   // z; y written in place
  float* XC    = (float*)alloc((size_t)ROWS*DINNER*4);   // post conv+silu x
  float* XDBL  = (float*)alloc((size_t)ROWS*NDBL*4);
  float* HLOC  = (float*)alloc((size_t)BATCH*NC*DINNER*16*4);
  float* SSUM  = (float*)alloc((size_t)BATCH*NC*DINNER*4);
  float* XPART = (float*)alloc((size_t)KSPLIT*ROWS*128*4);

  hipMemsetAsync(WQx, 0, (size_t)128*2048*2, stream);

  const int n_in_w  = 4096*1024;
  const int n_x_w   = NDBL*DINNER;
  const int n_out_w = 1024*2048;
  absmean_partial_k<<<512,256,0,stream>>>(in_proj_w,  n_in_w,  part0);
  absmean_final_k<<<1,256,0,stream>>>(part0, (float)n_in_w,  wsc+0);
  ternarize4_k<<<(n_in_w/4)/256,256,0,stream>>>(in_proj_w, (ushort*)WQin, n_in_w/4, wsc+0);
  absmean_partial_k<<<512,256,0,stream>>>(x_proj_w,   n_x_w,   part1);
  absmean_final_k<<<1,256,0,stream>>>(part1, (float)n_x_w,   wsc+1);
  ternarize4_k<<<(n_x_w/4+255)/256,256,0,stream>>>(x_proj_w, (ushort*)WQx, n_x_w/4, wsc+1);
  absmean_partial_k<<<512,256,0,stream>>>(out_proj_w, n_out_w, part2);
  absmean_final_k<<<1,256,0,stream>>>(part2, (float)n_out_w, wsc+2);
  ternarize4_k<<<(n_out_w/4)/256,256,0,stream>>>(out_proj_w, (ushort*)WQout, n_out_w/4, wsc+2);

  // 1) rms_norm + LN + act-quant of hidden
  ln_quant_k<4><<<ROWS,256,0,stream>>>(hidden, rms_w, QA, RS);
  // 2) in_proj GEMM -> x (XBUF), z (ZBUF)   [512 blocks]
  gemm2_k<128,128,1><<<dim3(ROWS/128, 4096/128, 1),256,0,stream>>>((const short*)QA,
      (const short*)WQin, RS, DIM, DIM, 0, XBUF, ZBUF, nullptr);
  // 3) conv + silu
  conv_silu_k<<<(ROWS*DINNER)/256,256,0,stream>>>(XBUF, conv_w, conv_b, XC);
  // 4) LN + quant of conv output
  ln_quant_k<8><<<ROWS,256,0,stream>>>(XC, nullptr, QA, RS);
  // 5) x_proj GEMM split-K -> partials -> combine   [256 blocks]
  gemm2_k<64,128,3><<<dim3(ROWS/64, 1, KSPLIT),256,0,stream>>>((const short*)QA,
      (const short*)WQx, nullptr, DINNER, DINNER/KSPLIT, 0, XPART, nullptr, nullptr);
  xproj_combine_k<<<(ROWS*NDBL)/256,256,0,stream>>>(XPART, RS, XDBL);
  // 6) dt_proj + softplus -> delta (reuses XBUF)
  dt_delta_k<<<dim3(ROWS/32, DINNER/64),256,0,stream>>>(XDBL, dt_proj_w, dt_proj_b, XBUF);
  // 7) chunked selective scan; y over z in place
  scan1_k<<<dim3(DINNER/256, NC, BATCH),256,0,stream>>>(XBUF, XC, XDBL, A_log, HLOC, SSUM);
  scan2_k<<<(BATCH*DINNER*16)/256,256,0,stream>>>(A_log, SSUM, HLOC);
  scan3_k<<<dim3(DINNER/256, NC, BATCH),256,0,stream>>>(XBUF, XC, XDBL, A_log, Dp, HLOC, ZBUF);
  // 8) LN + quant of y
  ln_quant_k<8><<<ROWS,256,0,stream>>>(ZBUF, nullptr, QA, RS);
  // 9) out_proj GEMM + residual -> d_out   [512 blocks]
  gemm2_k<64,64,2><<<dim3(ROWS/64, 1024/64, 1),256,0,stream>>>((const short*)QA,
      (const short*)WQout, RS, DINNER, DINNER, DIM, (float*)d_out, nullptr, hidden);
}

// Round 4
// 200.814 us; speedup vs baseline: 4.3628x; 1.0812x over previous
//
#include <hip/hip_runtime.h>
#include <hip/hip_bf16.h>

#define BATCH 2
#define SEQ 1024
#define DIM 1024
#define DINNER 2048
#define NSTATE 16
#define DTRANK 64
#define NDBL 96
#define ROWS (BATCH*SEQ)
#define NC 32
#define TC 32
#define KSPLIT 8

typedef __attribute__((ext_vector_type(8))) short bf16x8;
typedef __attribute__((ext_vector_type(4))) float f32x4;

__device__ inline float wave_sum64(float v){
#pragma unroll
  for (int o=32;o>0;o>>=1) v += __shfl_xor(v,o,64);
  return v;
}
__device__ inline float wave_max64(float v){
#pragma unroll
  for (int o=32;o>0;o>>=1) v = fmaxf(v,__shfl_xor(v,o,64));
  return v;
}
__device__ inline float block_sum256(float v, float* sred){
  v = wave_sum64(v);
  if ((threadIdx.x&63)==0) sred[threadIdx.x>>6]=v;
  __syncthreads();
  float t = sred[0]+sred[1]+sred[2]+sred[3];
  __syncthreads();
  return t;
}
__device__ inline float block_max256(float v, float* sred){
  v = wave_max64(v);
  if ((threadIdx.x&63)==0) sred[threadIdx.x>>6]=v;
  __syncthreads();
  float t = fmaxf(fmaxf(sred[0],sred[1]),fmaxf(sred[2],sred[3]));
  __syncthreads();
  return t;
}

// ---------- weight ternarization ----------
__global__ __launch_bounds__(256) void absmean_partial_k(const float* __restrict__ w, int n,
                                                         float* __restrict__ part){
  __shared__ float sred[4];
  float s = 0.f;
  for (int i = blockIdx.x*256 + threadIdx.x; i < n; i += 512*256) s += fabsf(w[i]);
  s = block_sum256(s, sred);
  if (threadIdx.x==0) part[blockIdx.x] = s;
}
__global__ __launch_bounds__(256) void absmean_final_k(const float* __restrict__ part,
                                                       float count, float* __restrict__ out){
  __shared__ float sred[4];
  float s = part[threadIdx.x] + part[threadIdx.x+256];
  s = block_sum256(s, sred);
  if (threadIdx.x==0) *out = fmaxf(s/count, 1e-5f);
}
__global__ __launch_bounds__(256) void ternarize4_k(const float* __restrict__ w,
                                                    ushort* __restrict__ wq, int n4,
                                                    const float* __restrict__ scale){
  int i = blockIdx.x*256 + threadIdx.x;
  if (i<n4){
    const float s = *scale;
    const float4 v = ((const float4*)w)[i];
    float q0 = fminf(fmaxf(rintf(v.x/s),-1.f),1.f);
    float q1 = fminf(fmaxf(rintf(v.y/s),-1.f),1.f);
    float q2 = fminf(fmaxf(rintf(v.z/s),-1.f),1.f);
    float q3 = fminf(fmaxf(rintf(v.w/s),-1.f),1.f);
    __hip_bfloat16 h0=__float2bfloat16(q0), h1=__float2bfloat16(q1);
    __hip_bfloat16 h2=__float2bfloat16(q2), h3=__float2bfloat16(q3);
    ushort4 o;
    o.x=*(ushort*)&h0; o.y=*(ushort*)&h1; o.z=*(ushort*)&h2; o.w=*(ushort*)&h3;
    ((ushort4*)wq)[i]=o;
  }
}

// ---------- fused (optional rms_norm) + LayerNorm + activation int8 fake-quant ----------
template<int NV>
__global__ __launch_bounds__(256) void ln_quant_k(const float* __restrict__ src,
    const float* __restrict__ rmsw, __hip_bfloat16* __restrict__ q, float* __restrict__ rs){
  constexpr int C = NV*256;
  __shared__ float sred[4];
  const int r = blockIdx.x, tid = threadIdx.x;
  const float* row = src + (size_t)r*C;
  float v[NV];
#pragma unroll
  for (int i=0;i<NV;i++) v[i] = row[tid + i*256];
  if (rmsw){
    float ss=0.f;
#pragma unroll
    for (int i=0;i<NV;i++) ss += v[i]*v[i];
    ss = block_sum256(ss, sred);
    float f = rsqrtf(ss/(float)C + 1e-6f);
#pragma unroll
    for (int i=0;i<NV;i++) v[i] *= f * rmsw[tid + i*256];
  }
  float s=0.f;
#pragma unroll
  for (int i=0;i<NV;i++) s += v[i];
  s = block_sum256(s, sred);
  const float mu = s/(float)C;
  float vs=0.f;
#pragma unroll
  for (int i=0;i<NV;i++){ float d=v[i]-mu; vs += d*d; }
  vs = block_sum256(vs, sred);
  const float inv = rsqrtf(vs/(float)C + 1e-5f);
  float am=0.f;
#pragma unroll
  for (int i=0;i<NV;i++){ v[i] = (v[i]-mu)*inv; am = fmaxf(am, fabsf(v[i])); }
  am = block_max256(am, sred);
  am = fmaxf(am, 1e-5f);
  const float scale = 127.f/am;
  if (tid==0) rs[r] = am*(1.f/127.f);
#pragma unroll
  for (int i=0;i<NV;i++){
    float qv = fminf(fmaxf(rintf(v[i]*scale), -128.f), 127.f);
    q[(size_t)r*C + tid + i*256] = __float2bfloat16(qv);
  }
}

// ---------- fused depthwise causal conv1d + silu + LayerNorm + act quant ----------
// one block per row r; writes XC row (for scans) AND quantized row + rs.
__global__ __launch_bounds__(256) void conv_ln_quant_k(const float* __restrict__ x,
    const float* __restrict__ cw, const float* __restrict__ cb,
    float* __restrict__ xc, __hip_bfloat16* __restrict__ q, float* __restrict__ rs){
  __shared__ float sred[4];
  const int r = blockIdx.x, tid = threadIdx.x;
  const int t = r & (SEQ-1);
  float v[8];
#pragma unroll
  for (int i=0;i<8;i++){
    const int d = tid + i*256;
    const float4 w4 = ((const float4*)cw)[d];
    const float wj[4] = {w4.x, w4.y, w4.z, w4.w};
    float acc = cb[d];
#pragma unroll
    for (int j=0;j<4;j++){
      const int tt = t-3+j;
      if (tt>=0) acc += x[(size_t)(r-3+j)*DINNER + d]*wj[j];
    }
    acc = acc/(1.f+expf(-acc));
    xc[(size_t)r*DINNER + d] = acc;
    v[i] = acc;
  }
  float s=0.f;
#pragma unroll
  for (int i=0;i<8;i++) s += v[i];
  s = block_sum256(s, sred);
  const float mu = s/2048.f;
  float vs=0.f;
#pragma unroll
  for (int i=0;i<8;i++){ float d=v[i]-mu; vs += d*d; }
  vs = block_sum256(vs, sred);
  const float inv = rsqrtf(vs/2048.f + 1e-5f);
  float am=0.f;
#pragma unroll
  for (int i=0;i<8;i++){ v[i] = (v[i]-mu)*inv; am = fmaxf(am, fabsf(v[i])); }
  am = block_max256(am, sred);
  am = fmaxf(am, 1e-5f);
  const float scale = 127.f/am;
  if (tid==0) rs[r] = am*(1.f/127.f);
#pragma unroll
  for (int i=0;i<8;i++){
    float qv = fminf(fmaxf(rintf(v[i]*scale), -128.f), 127.f);
    q[(size_t)r*2048 + tid + i*256] = __float2bfloat16(qv);
  }
}

// ---------- bf16 MFMA GEMM, BK=64, swizzled LDS ----------
template<int BM, int BN, int MODE>
__global__ __launch_bounds__(256) void gemm2_k(
    const short* __restrict__ A, const short* __restrict__ Bw,
    const float* __restrict__ rs, int K, int Ksub, int ldc,
    float* __restrict__ out0, float* __restrict__ out1,
    const float* __restrict__ hid)
{
  constexpr int MF = BM/32;
  constexpr int NF = BN/32;
  constexpr int CA = BM/32;
  constexpr int CB = BN/32;
  __shared__ short lsA[BM*64];
  __shared__ short lsB[BN*64];
  const int tid = threadIdx.x;
  const int w = tid>>6, l = tid&63;
  const int m0 = blockIdx.x*BM, n0 = blockIdx.y*BN;
  const int wr = (w>>1)*(BM/2), wc = (w&1)*(BN/2);
  const int lr = l&15, g = l>>4;
  f32x4 acc[MF][NF];
#pragma unroll
  for (int m=0;m<MF;m++)
#pragma unroll
    for (int n=0;n<NF;n++) acc[m][n] = (f32x4){0.f,0.f,0.f,0.f};

  const size_t KB = (size_t)K*2;
  const char* Ag = (const char*)A + (size_t)m0*KB + (size_t)blockIdx.z*Ksub*2;
  const char* Bg = (const char*)Bw + (size_t)n0*KB + (size_t)blockIdx.z*Ksub*2;

  bf16x8 ra[CA], rb[CB];
#define LDG(kb)                                                                   \
  {                                                                               \
    _Pragma("unroll")                                                             \
    for (int c=0;c<CA;c++){ int o=c*4096+tid*16; int rw=o>>7, cl=o&127;           \
      ra[c] = *(const bf16x8*)(Ag + (size_t)rw*KB + (size_t)(kb)*2 + cl); }       \
    _Pragma("unroll")                                                             \
    for (int c=0;c<CB;c++){ int o=c*4096+tid*16; int rw=o>>7, cl=o&127;           \
      rb[c] = *(const bf16x8*)(Bg + (size_t)rw*KB + (size_t)(kb)*2 + cl); }       \
  }

  LDG(0);
  for (int kb=0; kb<Ksub; kb+=64){
    __syncthreads();
#pragma unroll
    for (int c=0;c<CA;c++){ int o=c*4096+tid*16; int rw=o>>7, sl=(o>>4)&7;
      *(bf16x8*)((char*)lsA + (rw<<7) + ((sl^(rw&7))<<4)) = ra[c]; }
#pragma unroll
    for (int c=0;c<CB;c++){ int o=c*4096+tid*16; int rw=o>>7, sl=(o>>4)&7;
      *(bf16x8*)((char*)lsB + (rw<<7) + ((sl^(rw&7))<<4)) = rb[c]; }
    __syncthreads();
    if (kb + 64 < Ksub) LDG(kb+64);
#pragma unroll
    for (int ks=0;ks<2;ks++){
      bf16x8 af[MF], bb[NF];
#pragma unroll
      for (int m=0;m<MF;m++){ int rw = wr + m*16 + lr;
        af[m] = *(const bf16x8*)((const char*)lsA + (rw<<7) + ((((ks<<2)+g)^(lr&7))<<4)); }
#pragma unroll
      for (int n=0;n<NF;n++){ int rw = wc + n*16 + lr;
        bb[n] = *(const bf16x8*)((const char*)lsB + (rw<<7) + ((((ks<<2)+g)^(lr&7))<<4)); }
#pragma unroll
      for (int m=0;m<MF;m++)
#pragma unroll
        for (int n=0;n<NF;n++)
          acc[m][n] = __builtin_amdgcn_mfma_f32_16x16x32_bf16(af[m], bb[n], acc[m][n], 0, 0, 0);
    }
  }
#undef LDG

#pragma unroll
  for (int m=0;m<MF;m++){
    const int rowb = m0 + wr + m*16 + g*4;
#pragma unroll
    for (int j=0;j<4;j++){
      const int row = rowb + j;
      const float rsv = (MODE==3) ? 1.f : rs[row];
#pragma unroll
      for (int n=0;n<NF;n++){
        const int col = n0 + wc + n*16 + lr;
        const float v = acc[m][n][j]*rsv;
        if (MODE==1){
          if (col < 2048) out0[(size_t)row*2048 + col] = v;
          else            out1[(size_t)row*2048 + (col-2048)] = v;
        } else if (MODE==2){
          const size_t o = (size_t)row*ldc + col;
          out0[o] = hid[o] + v;
        } else {
          out0[((size_t)blockIdx.z*2048 + row)*128 + col] = v;
        }
      }
    }
  }
}

// combine split-K partials for x_proj
__global__ __launch_bounds__(256) void xproj_combine_k(const float* __restrict__ part,
    const float* __restrict__ rs, float* __restrict__ xdbl){
  const int idx = blockIdx.x*256 + threadIdx.x;
  const int row = idx/NDBL, c = idx - row*NDBL;
  float s = 0.f;
#pragma unroll
  for (int z=0; z<KSPLIT; z++) s += part[((size_t)z*ROWS + row)*128 + c];
  xdbl[(size_t)idx] = s * rs[row];
}

// ---------- dt_proj + softplus, register-blocked ----------
// block: 128 rows x 64 cols; thread: 8 rows x 4 cols. LDS holds X^T and W^T.
#define SXT_S 130
#define SW2_S 66
__global__ __launch_bounds__(256) void dt_delta2_k(const float* __restrict__ xdbl,
    const float* __restrict__ W, const float* __restrict__ bias, float* __restrict__ delta){
  __shared__ float sXT[64*SXT_S];
  __shared__ float sW2[64*SW2_S];
  const int tid = threadIdx.x;
  const int r0 = blockIdx.x*128, d0 = blockIdx.y*64;
  // stage X^T: read [row][k] float4, write 4 scalars to sXT[k][row]
#pragma unroll
  for (int qit=0;qit<8;qit++){
    const int f4 = qit*256 + tid;
    const int rr = f4>>4, k0 = (f4&15)<<2;
    const float4 xv4 = *(const float4*)(xdbl + (size_t)(r0+rr)*NDBL + k0);
    sXT[(k0+0)*SXT_S + rr] = xv4.x;
    sXT[(k0+1)*SXT_S + rr] = xv4.y;
    sXT[(k0+2)*SXT_S + rr] = xv4.z;
    sXT[(k0+3)*SXT_S + rr] = xv4.w;
  }
  // stage W^T: read [d][k] float4, write to sW2[k][d]
#pragma unroll
  for (int qit=0;qit<4;qit++){
    const int f4 = qit*256 + tid;
    const int dd = f4>>4, k0 = (f4&15)<<2;
    const float4 wv4 = *(const float4*)(W + (size_t)(d0+dd)*64 + k0);
    sW2[(k0+0)*SW2_S + dd] = wv4.x;
    sW2[(k0+1)*SW2_S + dd] = wv4.y;
    sW2[(k0+2)*SW2_S + dd] = wv4.z;
    sW2[(k0+3)*SW2_S + dd] = wv4.w;
  }
  __syncthreads();
  const int tx = tid&15, ty = tid>>4;       // ty: row group, tx: col group
  float acc[8][4];
#pragma unroll
  for (int i=0;i<8;i++)
#pragma unroll
    for (int j=0;j<4;j++) acc[i][j]=0.f;
  for (int k=0;k<64;k++){
    float xv[8], wv[4];
    *(float2*)&xv[0] = *(const float2*)&sXT[k*SXT_S + ty*8 + 0];
    *(float2*)&xv[2] = *(const float2*)&sXT[k*SXT_S + ty*8 + 2];
    *(float2*)&xv[4] = *(const float2*)&sXT[k*SXT_S + ty*8 + 4];
    *(float2*)&xv[6] = *(const float2*)&sXT[k*SXT_S + ty*8 + 6];
    *(float2*)&wv[0] = *(const float2*)&sW2[k*SW2_S + tx*4 + 0];
    *(float2*)&wv[2] = *(const float2*)&sW2[k*SW2_S + tx*4 + 2];
#pragma unroll
    for (int i=0;i<8;i++)
#pragma unroll
      for (int j=0;j<4;j++) acc[i][j] = fmaf(xv[i], wv[j], acc[i][j]);
  }
  const float4 b4 = *(const float4*)(bias + d0 + tx*4);
  const float b2[4] = {2.f*b4.x, 2.f*b4.y, 2.f*b4.z, 2.f*b4.w};
#pragma unroll
  for (int i=0;i<8;i++){
    const int row = r0 + ty*8 + i;
    float4 o;
    float* op = (float*)&o;
#pragma unroll
    for (int j=0;j<4;j++){
      const float xq = acc[i][j] + b2[j];
      op[j] = (xq>20.f) ? xq : log1pf(expf(xq));
    }
    *(float4*)(delta + (size_t)row*DINNER + d0 + tx*4) = o;
  }
}

// ---------- chunked selective scan ----------
__global__ __launch_bounds__(256) void scan1_k(const float* __restrict__ delta,
    const float* __restrict__ xc, const float* __restrict__ xdbl,
    const float* __restrict__ A_log, float* __restrict__ hloc, float* __restrict__ Ssum){
  __shared__ float sB[TC][16];
  const int tid = threadIdx.x;
  const int d = blockIdx.x*256 + tid;
  const int c = blockIdx.y, b = blockIdx.z;
  const int row0 = b*SEQ + c*TC;
  for (int i=tid;i<TC*16;i+=256){
    int t=i>>4, j=i&15;
    sB[t][j] = xdbl[(size_t)(row0+t)*NDBL + DTRANK + j];
  }
  __syncthreads();
  float a[16];
  const f32x4* Ap = (const f32x4*)(A_log + (size_t)d*16);
#pragma unroll
  for (int q=0;q<4;q++){
    f32x4 av = Ap[q];
#pragma unroll
    for (int j=0;j<4;j++) a[q*4+j] = -__expf(av[j]);
  }
  float h[16];
#pragma unroll
  for (int n=0;n<16;n++) h[n]=0.f;
  float S = 0.f;
  float dl = delta[(size_t)row0*DINNER + d];
  float xv = xc[(size_t)row0*DINNER + d];
  for (int t=0;t<TC;t++){
    const float dlc=dl, xvc=xv;
    if (t<TC-1){
      dl = delta[(size_t)(row0+t+1)*DINNER + d];
      xv = xc[(size_t)(row0+t+1)*DINNER + d];
    }
    S += dlc;
    const float dx = dlc*xvc;
#pragma unroll
    for (int n=0;n<16;n++)
      h[n] = fmaf(__expf(dlc*a[n]), h[n], dx*sB[t][n]);
  }
  f32x4* hp = (f32x4*)(hloc + ((size_t)(b*NC+c)*DINNER + d)*16);
#pragma unroll
  for (int q=0;q<4;q++){
    f32x4 hv;
#pragma unroll
    for (int j=0;j<4;j++) hv[j]=h[q*4+j];
    hp[q]=hv;
  }
  Ssum[(size_t)(b*NC+c)*DINNER + d] = S;
}

__global__ __launch_bounds__(256) void scan2_k(const float* __restrict__ A_log,
    const float* __restrict__ Ssum, float* __restrict__ hloc){
  const int idx = blockIdx.x*256 + threadIdx.x;
  const int n = idx&15, d = (idx>>4)&(DINNER-1), b = idx>>15;
  const float a = -__expf(A_log[(size_t)d*16+n]);
  float hin = 0.f;
  for (int c=0;c<NC;c++){
    const size_t o = ((size_t)(b*NC+c)*DINNER + d)*16 + n;
    const float t = hloc[o];
    hloc[o] = hin;
    hin = fmaf(__expf(a*Ssum[(size_t)(b*NC+c)*DINNER + d]), hin, t);
  }
}

__global__ __launch_bounds__(256) void scan3_k(const float* __restrict__ delta,
    const float* __restrict__ xc, const float* __restrict__ xdbl,
    const float* __restrict__ A_log, const float* __restrict__ Dp,
    const float* __restrict__ hloc, float* __restrict__ zy){
  __shared__ float sBC[TC][32];
  const int tid = threadIdx.x;
  const int d = blockIdx.x*256 + tid;
  const int c = blockIdx.y, b = blockIdx.z;
  const int row0 = b*SEQ + c*TC;
  for (int i=tid;i<TC*32;i+=256){
    int t=i>>5, j=i&31;
    sBC[t][j] = xdbl[(size_t)(row0+t)*NDBL + DTRANK + j];
  }
  __syncthreads();
  float a[16];
  const f32x4* Ap = (const f32x4*)(A_log + (size_t)d*16);
#pragma unroll
  for (int q=0;q<4;q++){
    f32x4 av = Ap[q];
#pragma unroll
    for (int j=0;j<4;j++) a[q*4+j] = -__expf(av[j]);
  }
  float h[16];
  const f32x4* hp = (const f32x4*)(hloc + ((size_t)(b*NC+c)*DINNER + d)*16);
#pragma unroll
  for (int q=0;q<4;q++){
    f32x4 hv = hp[q];
#pragma unroll
    for (int j=0;j<4;j++) h[q*4+j]=hv[j];
  }
  const float Dv = Dp[d];
  float dl = delta[(size_t)row0*DINNER + d];
  float xv = xc[(size_t)row0*DINNER + d];
  float zv = zy[(size_t)row0*DINNER + d];
  for (int t=0;t<TC;t++){
    const float dlc=dl, xvc=xv, zvc=zv;
    if (t<TC-1){
      dl = delta[(size_t)(row0+t+1)*DINNER + d];
      xv = xc[(size_t)(row0+t+1)*DINNER + d];
      zv = zy[(size_t)(row0+t+1)*DINNER + d];
    }
    const float dx = dlc*xvc;
    float p = 0.f;
#pragma unroll
    for (int n=0;n<16;n++){
      h[n] = fmaf(__expf(dlc*a[n]), h[n], dx*sBC[t][n]);
      p = fmaf(h[n], sBC[t][16+n], p);
    }
    float y = p + xvc*Dv;
    y *= zvc/(1.f+__expf(-zvc));
    zy[(size_t)(row0+t)*DINNER + d] = y;
  }
}

extern "C" void kernel_launch(void* const* d_in, const int* in_sizes, int n_in,
                              void* d_out, int out_size, void* d_ws, size_t ws_size,
                              hipStream_t stream){
  (void)in_sizes; (void)n_in; (void)out_size; (void)ws_size;
  const float* hidden    = (const float*)d_in[0];
  const float* rms_w     = (const float*)d_in[1];
  const float* in_proj_w = (const float*)d_in[2];
  const float* x_proj_w  = (const float*)d_in[3];
  const float* out_proj_w= (const float*)d_in[4];
  const float* conv_w    = (const float*)d_in[5];
  const float* conv_b    = (const float*)d_in[6];
  const float* dt_proj_w = (const float*)d_in[7];
  const float* dt_proj_b = (const float*)d_in[8];
  const float* A_log     = (const float*)d_in[9];
  const float* Dp        = (const float*)d_in[10];

  char* ws = (char*)d_ws; size_t off = 0;
  auto alloc = [&](size_t b)->void* { void* p = ws + off; off += (b + 255) & ~(size_t)255; return p; };
  float* part0 = (float*)alloc(512*4);
  float* part1 = (float*)alloc(512*4);
  float* part2 = (float*)alloc(512*4);
  float* wsc   = (float*)alloc(256);
  float* RS    = (float*)alloc((size_t)ROWS*4);
  __hip_bfloat16* WQin  = (__hip_bfloat16*)alloc((size_t)4096*1024*2);
  __hip_bfloat16* WQx   = (__hip_bfloat16*)alloc((size_t)128*2048*2);
  __hip_bfloat16* WQout = (__hip_bfloat16*)alloc((size_t)1024*2048*2);
  __hip_bfloat16* QA    = (__hip_bfloat16*)alloc((size_t)ROWS*2048*2);
  float* XBUF  = (float*)alloc((size_t)ROWS*DINNER*4);
  float* ZBUF  = (float*)alloc((size_t)ROWS*DINNER*4);
  float* XC    = (float*)alloc((size_t)ROWS*DINNER*4);
  float* XDBL  = (float*)alloc((size_t)ROWS*NDBL*4);
  float* HLOC  = (float*)alloc((size_t)BATCH*NC*DINNER*16*4);
  float* SSUM  = (float*)alloc((size_t)BATCH*NC*DINNER*4);
  float* XPART = (float*)alloc((size_t)KSPLIT*ROWS*128*4);

  hipMemsetAsync(WQx, 0, (size_t)128*2048*2, stream);

  const int n_in_w  = 4096*1024;
  const int n_x_w   = NDBL*DINNER;
  const int n_out_w = 1024*2048;
  absmean_partial_k<<<512,256,0,stream>>>(in_proj_w,  n_in_w,  part0);
  absmean_final_k<<<1,256,0,stream>>>(part0, (float)n_in_w,  wsc+0);
  ternarize4_k<<<(n_in_w/4)/256,256,0,stream>>>(in_proj_w, (ushort*)WQin, n_in_w/4, wsc+0);
  absmean_partial_k<<<512,256,0,stream>>>(x_proj_w,   n_x_w,   part1);
  absmean_final_k<<<1,256,0,stream>>>(part1, (float)n_x_w,   wsc+1);
  ternarize4_k<<<(n_x_w/4+255)/256,256,0,stream>>>(x_proj_w, (ushort*)WQx, n_x_w/4, wsc+1);
  absmean_partial_k<<<512,256,0,stream>>>(out_proj_w, n_out_w, part2);
  absmean_final_k<<<1,256,0,stream>>>(part2, (float)n_out_w, wsc+2);
  ternarize4_k<<<(n_out_w/4)/256,256,0,stream>>>(out_proj_w, (ushort*)WQout, n_out_w/4, wsc+2);

  // 1) rms_norm + LN + act-quant of hidden
  ln_quant_k<4><<<ROWS,256,0,stream>>>(hidden, rms_w, QA, RS);
  // 2) in_proj GEMM -> x (XBUF), z (ZBUF)
  gemm2_k<128,128,1><<<dim3(ROWS/128, 4096/128, 1),256,0,stream>>>((const short*)QA,
      (const short*)WQin, RS, DIM, DIM, 0, XBUF, ZBUF, nullptr);
  // 3+4) fused conv + silu + LN + quant (writes XC and QA/RS)
  conv_ln_quant_k<<<ROWS,256,0,stream>>>(XBUF, conv_w, conv_b, XC, QA, RS);
  // 5) x_proj GEMM split-K -> partials -> combine
  gemm2_k<64,128,3><<<dim3(ROWS/64, 1, KSPLIT),256,0,stream>>>((const short*)QA,
      (const short*)WQx, nullptr, DINNER, DINNER/KSPLIT, 0, XPART, nullptr, nullptr);
  xproj_combine_k<<<(ROWS*NDBL)/256,256,0,stream>>>(XPART, RS, XDBL);
  // 6) dt_proj + softplus -> delta (reuses XBUF)
  dt_delta2_k<<<dim3(ROWS/128, DINNER/64),256,0,stream>>>(XDBL, dt_proj_w, dt_proj_b, XBUF);
  // 7) chunked selective scan; y over z in place
  scan1_k<<<dim3(DINNER/256, NC, BATCH),256,0,stream>>>(XBUF, XC, XDBL, A_log, HLOC, SSUM);
  scan2_k<<<(BATCH*DINNER*16)/256,256,0,stream>>>(A_log, SSUM, HLOC);
  scan3_k<<<dim3(DINNER/256, NC, BATCH),256,0,stream>>>(XBUF, XC, XDBL, A_log, Dp, HLOC, ZBUF);
  // 8) LN + quant of y
  ln_quant_k<8><<<ROWS,256,0,stream>>>(ZBUF, nullptr, QA, RS);
  // 9) out_proj GEMM + residual -> d_out
  gemm2_k<64,64,2><<<dim3(ROWS/64, 1024/64, 1),256,0,stream>>>((const short*)QA,
      (const short*)WQout, RS, DINNER, DINNER, DIM, (float*)d_out, nullptr, hidden);
}

// Round 5
// 181.314 us; speedup vs baseline: 4.8320x; 1.1075x over previous
//
#include <hip/hip_runtime.h>
#include <hip/hip_bf16.h>

#define BATCH 2
#define SEQ 1024
#define DIM 1024
#define DINNER 2048
#define NSTATE 16
#define DTRANK 64
#define NDBL 96
#define ROWS (BATCH*SEQ)
#define NC 32
#define TC 32
#define KSPLIT 8

#define N_IN_W  (4096*1024)
#define N_X_W   (NDBL*DINNER)
#define N_OUT_W (1024*2048)

typedef __attribute__((ext_vector_type(8))) short bf16x8;
typedef __attribute__((ext_vector_type(4))) float f32x4;

__device__ inline float wave_sum64(float v){
#pragma unroll
  for (int o=32;o>0;o>>=1) v += __shfl_xor(v,o,64);
  return v;
}
__device__ inline float wave_max64(float v){
#pragma unroll
  for (int o=32;o>0;o>>=1) v = fmaxf(v,__shfl_xor(v,o,64));
  return v;
}
__device__ inline float block_sum256(float v, float* sred){
  v = wave_sum64(v);
  if ((threadIdx.x&63)==0) sred[threadIdx.x>>6]=v;
  __syncthreads();
  float t = sred[0]+sred[1]+sred[2]+sred[3];
  __syncthreads();
  return t;
}
__device__ inline float block_max256(float v, float* sred){
  v = wave_max64(v);
  if ((threadIdx.x&63)==0) sred[threadIdx.x>>6]=v;
  __syncthreads();
  float t = fmaxf(fmaxf(sred[0],sred[1]),fmaxf(sred[2],sred[3]));
  __syncthreads();
  return t;
}

// ---------- weight ternarization (fused 3-weight pipeline) ----------
__global__ __launch_bounds__(256) void absmean3_partial_k(const float* __restrict__ w0,
    const float* __restrict__ w1, const float* __restrict__ w2, float* __restrict__ part){
  __shared__ float sred[4];
  const float* w; int n;
  if (blockIdx.y==0){ w=w0; n=N_IN_W; }
  else if (blockIdx.y==1){ w=w1; n=N_X_W; }
  else { w=w2; n=N_OUT_W; }
  float s = 0.f;
  for (int i = blockIdx.x*256 + threadIdx.x; i < n; i += 512*256) s += fabsf(w[i]);
  s = block_sum256(s, sred);
  if (threadIdx.x==0) part[blockIdx.y*512 + blockIdx.x] = s;
}
__global__ __launch_bounds__(256) void absmean3_final_k(const float* __restrict__ part,
                                                        float* __restrict__ out){
  __shared__ float sred[4];
  const float cnt0 = (float)N_IN_W, cnt1 = (float)N_X_W, cnt2 = (float)N_OUT_W;
#pragma unroll
  for (int w=0; w<3; w++){
    float s = part[w*512 + threadIdx.x] + part[w*512 + threadIdx.x + 256];
    s = block_sum256(s, sred);
    if (threadIdx.x==0){
      const float c = (w==0)?cnt0:((w==1)?cnt1:cnt2);
      out[w] = fmaxf(s/c, 1e-5f);
    }
  }
}
__device__ inline void tern4(const float* __restrict__ w, ushort* __restrict__ wq,
                             int i, float s){
  const float4 v = ((const float4*)w)[i];
  float q0 = fminf(fmaxf(rintf(v.x/s),-1.f),1.f);
  float q1 = fminf(fmaxf(rintf(v.y/s),-1.f),1.f);
  float q2 = fminf(fmaxf(rintf(v.z/s),-1.f),1.f);
  float q3 = fminf(fmaxf(rintf(v.w/s),-1.f),1.f);
  __hip_bfloat16 h0=__float2bfloat16(q0), h1=__float2bfloat16(q1);
  __hip_bfloat16 h2=__float2bfloat16(q2), h3=__float2bfloat16(q3);
  ushort4 o;
  o.x=*(ushort*)&h0; o.y=*(ushort*)&h1; o.z=*(ushort*)&h2; o.w=*(ushort*)&h3;
  ((ushort4*)wq)[i]=o;
}
// covers all 3 weights (float4 granularity) + zero pad rows of WQx
__global__ __launch_bounds__(256) void ternarize3_k(const float* __restrict__ w0,
    const float* __restrict__ w1, const float* __restrict__ w2,
    ushort* __restrict__ q0, ushort* __restrict__ q1, ushort* __restrict__ q2,
    const float* __restrict__ wsc){
  const int NQ0 = N_IN_W/4, NQ1 = N_X_W/4, PQ1 = (128*2048 - N_X_W)/4, NQ2 = N_OUT_W/4;
  int i = blockIdx.x*256 + threadIdx.x;
  if (i < NQ0){ tern4(w0, q0, i, wsc[0]); return; }
  i -= NQ0;
  if (i < NQ1){ tern4(w1, q1, i, wsc[1]); return; }
  i -= NQ1;
  if (i < PQ1){ ((ushort4*)q1)[NQ1 + i] = (ushort4){0,0,0,0}; return; }
  i -= PQ1;
  if (i < NQ2){ tern4(w2, q2, i, wsc[2]); }
}

// ---------- fused (optional rms_norm) + LayerNorm + activation int8 fake-quant ----------
template<int NV>
__global__ __launch_bounds__(256) void ln_quant_k(const float* __restrict__ src,
    const float* __restrict__ rmsw, __hip_bfloat16* __restrict__ q, float* __restrict__ rs){
  constexpr int C = NV*256;
  __shared__ float sred[4];
  const int r = blockIdx.x, tid = threadIdx.x;
  const float* row = src + (size_t)r*C;
  float v[NV];
#pragma unroll
  for (int i=0;i<NV;i++) v[i] = row[tid + i*256];
  if (rmsw){
    float ss=0.f;
#pragma unroll
    for (int i=0;i<NV;i++) ss += v[i]*v[i];
    ss = block_sum256(ss, sred);
    float f = rsqrtf(ss/(float)C + 1e-6f);
#pragma unroll
    for (int i=0;i<NV;i++) v[i] *= f * rmsw[tid + i*256];
  }
  float s=0.f;
#pragma unroll
  for (int i=0;i<NV;i++) s += v[i];
  s = block_sum256(s, sred);
  const float mu = s/(float)C;
  float vs=0.f;
#pragma unroll
  for (int i=0;i<NV;i++){ float d=v[i]-mu; vs += d*d; }
  vs = block_sum256(vs, sred);
  const float inv = rsqrtf(vs/(float)C + 1e-5f);
  float am=0.f;
#pragma unroll
  for (int i=0;i<NV;i++){ v[i] = (v[i]-mu)*inv; am = fmaxf(am, fabsf(v[i])); }
  am = block_max256(am, sred);
  am = fmaxf(am, 1e-5f);
  const float scale = 127.f/am;
  if (tid==0) rs[r] = am*(1.f/127.f);
#pragma unroll
  for (int i=0;i<NV;i++){
    float qv = fminf(fmaxf(rintf(v[i]*scale), -128.f), 127.f);
    q[(size_t)r*C + tid + i*256] = __float2bfloat16(qv);
  }
}

// ---------- fused depthwise causal conv1d + silu + LayerNorm + act quant ----------
__global__ __launch_bounds__(256) void conv_ln_quant_k(const float* __restrict__ x,
    const float* __restrict__ cw, const float* __restrict__ cb,
    float* __restrict__ xc, __hip_bfloat16* __restrict__ q, float* __restrict__ rs){
  __shared__ float sred[4];
  const int r = blockIdx.x, tid = threadIdx.x;
  const int t = r & (SEQ-1);
  float v[8];
#pragma unroll
  for (int i=0;i<8;i++){
    const int d = tid + i*256;
    const float4 w4 = ((const float4*)cw)[d];
    const float wj[4] = {w4.x, w4.y, w4.z, w4.w};
    float acc = cb[d];
#pragma unroll
    for (int j=0;j<4;j++){
      const int tt = t-3+j;
      if (tt>=0) acc += x[(size_t)(r-3+j)*DINNER + d]*wj[j];
    }
    acc = acc/(1.f+expf(-acc));
    xc[(size_t)r*DINNER + d] = acc;
    v[i] = acc;
  }
  float s=0.f;
#pragma unroll
  for (int i=0;i<8;i++) s += v[i];
  s = block_sum256(s, sred);
  const float mu = s/2048.f;
  float vs=0.f;
#pragma unroll
  for (int i=0;i<8;i++){ float d=v[i]-mu; vs += d*d; }
  vs = block_sum256(vs, sred);
  const float inv = rsqrtf(vs/2048.f + 1e-5f);
  float am=0.f;
#pragma unroll
  for (int i=0;i<8;i++){ v[i] = (v[i]-mu)*inv; am = fmaxf(am, fabsf(v[i])); }
  am = block_max256(am, sred);
  am = fmaxf(am, 1e-5f);
  const float scale = 127.f/am;
  if (tid==0) rs[r] = am*(1.f/127.f);
#pragma unroll
  for (int i=0;i<8;i++){
    float qv = fminf(fmaxf(rintf(v[i]*scale), -128.f), 127.f);
    q[(size_t)r*2048 + tid + i*256] = __float2bfloat16(qv);
  }
}

// ---------- bf16 MFMA GEMM, BK=64, swizzled LDS ----------
template<int BM, int BN, int MODE>
__global__ __launch_bounds__(256) void gemm2_k(
    const short* __restrict__ A, const short* __restrict__ Bw,
    const float* __restrict__ rs, int K, int Ksub, int ldc,
    float* __restrict__ out0, float* __restrict__ out1,
    const float* __restrict__ hid)
{
  constexpr int MF = BM/32;
  constexpr int NF = BN/32;
  constexpr int CA = BM/32;
  constexpr int CB = BN/32;
  __shared__ short lsA[BM*64];
  __shared__ short lsB[BN*64];
  const int tid = threadIdx.x;
  const int w = tid>>6, l = tid&63;
  const int m0 = blockIdx.x*BM, n0 = blockIdx.y*BN;
  const int wr = (w>>1)*(BM/2), wc = (w&1)*(BN/2);
  const int lr = l&15, g = l>>4;
  f32x4 acc[MF][NF];
#pragma unroll
  for (int m=0;m<MF;m++)
#pragma unroll
    for (int n=0;n<NF;n++) acc[m][n] = (f32x4){0.f,0.f,0.f,0.f};

  const size_t KB = (size_t)K*2;
  const char* Ag = (const char*)A + (size_t)m0*KB + (size_t)blockIdx.z*Ksub*2;
  const char* Bg = (const char*)Bw + (size_t)n0*KB + (size_t)blockIdx.z*Ksub*2;

  bf16x8 ra[CA], rb[CB];
#define LDG(kb)                                                                   \
  {                                                                               \
    _Pragma("unroll")                                                             \
    for (int c=0;c<CA;c++){ int o=c*4096+tid*16; int rw=o>>7, cl=o&127;           \
      ra[c] = *(const bf16x8*)(Ag + (size_t)rw*KB + (size_t)(kb)*2 + cl); }       \
    _Pragma("unroll")                                                             \
    for (int c=0;c<CB;c++){ int o=c*4096+tid*16; int rw=o>>7, cl=o&127;           \
      rb[c] = *(const bf16x8*)(Bg + (size_t)rw*KB + (size_t)(kb)*2 + cl); }       \
  }

  LDG(0);
  for (int kb=0; kb<Ksub; kb+=64){
    __syncthreads();
#pragma unroll
    for (int c=0;c<CA;c++){ int o=c*4096+tid*16; int rw=o>>7, sl=(o>>4)&7;
      *(bf16x8*)((char*)lsA + (rw<<7) + ((sl^(rw&7))<<4)) = ra[c]; }
#pragma unroll
    for (int c=0;c<CB;c++){ int o=c*4096+tid*16; int rw=o>>7, sl=(o>>4)&7;
      *(bf16x8*)((char*)lsB + (rw<<7) + ((sl^(rw&7))<<4)) = rb[c]; }
    __syncthreads();
    if (kb + 64 < Ksub) LDG(kb+64);
#pragma unroll
    for (int ks=0;ks<2;ks++){
      bf16x8 af[MF], bb[NF];
#pragma unroll
      for (int m=0;m<MF;m++){ int rw = wr + m*16 + lr;
        af[m] = *(const bf16x8*)((const char*)lsA + (rw<<7) + ((((ks<<2)+g)^(lr&7))<<4)); }
#pragma unroll
      for (int n=0;n<NF;n++){ int rw = wc + n*16 + lr;
        bb[n] = *(const bf16x8*)((const char*)lsB + (rw<<7) + ((((ks<<2)+g)^(lr&7))<<4)); }
#pragma unroll
      for (int m=0;m<MF;m++)
#pragma unroll
        for (int n=0;n<NF;n++)
          acc[m][n] = __builtin_amdgcn_mfma_f32_16x16x32_bf16(af[m], bb[n], acc[m][n], 0, 0, 0);
    }
  }
#undef LDG

#pragma unroll
  for (int m=0;m<MF;m++){
    const int rowb = m0 + wr + m*16 + g*4;
#pragma unroll
    for (int j=0;j<4;j++){
      const int row = rowb + j;
      const float rsv = (MODE==3) ? 1.f : rs[row];
#pragma unroll
      for (int n=0;n<NF;n++){
        const int col = n0 + wc + n*16 + lr;
        const float v = acc[m][n][j]*rsv;
        if (MODE==1){
          if (col < 2048) out0[(size_t)row*2048 + col] = v;
          else            out1[(size_t)row*2048 + (col-2048)] = v;
        } else if (MODE==2){
          const size_t o = (size_t)row*ldc + col;
          out0[o] = hid[o] + v;
        } else {
          out0[((size_t)blockIdx.z*2048 + row)*128 + col] = v;
        }
      }
    }
  }
}

// combine split-K partials for x_proj
__global__ __launch_bounds__(256) void xproj_combine_k(const float* __restrict__ part,
    const float* __restrict__ rs, float* __restrict__ xdbl){
  const int idx = blockIdx.x*256 + threadIdx.x;
  const int row = idx/NDBL, c = idx - row*NDBL;
  float s = 0.f;
#pragma unroll
  for (int z=0; z<KSPLIT; z++) s += part[((size_t)z*ROWS + row)*128 + c];
  xdbl[(size_t)idx] = s * rs[row];
}

// ---------- dt_proj + softplus, register-blocked ----------
#define SXT_S 130
#define SW2_S 66
__global__ __launch_bounds__(256) void dt_delta2_k(const float* __restrict__ xdbl,
    const float* __restrict__ W, const float* __restrict__ bias, float* __restrict__ delta){
  __shared__ float sXT[64*SXT_S];
  __shared__ float sW2[64*SW2_S];
  const int tid = threadIdx.x;
  const int r0 = blockIdx.x*128, d0 = blockIdx.y*64;
#pragma unroll
  for (int qit=0;qit<8;qit++){
    const int f4 = qit*256 + tid;
    const int rr = f4>>4, k0 = (f4&15)<<2;
    const float4 xv4 = *(const float4*)(xdbl + (size_t)(r0+rr)*NDBL + k0);
    sXT[(k0+0)*SXT_S + rr] = xv4.x;
    sXT[(k0+1)*SXT_S + rr] = xv4.y;
    sXT[(k0+2)*SXT_S + rr] = xv4.z;
    sXT[(k0+3)*SXT_S + rr] = xv4.w;
  }
#pragma unroll
  for (int qit=0;qit<4;qit++){
    const int f4 = qit*256 + tid;
    const int dd = f4>>4, k0 = (f4&15)<<2;
    const float4 wv4 = *(const float4*)(W + (size_t)(d0+dd)*64 + k0);
    sW2[(k0+0)*SW2_S + dd] = wv4.x;
    sW2[(k0+1)*SW2_S + dd] = wv4.y;
    sW2[(k0+2)*SW2_S + dd] = wv4.z;
    sW2[(k0+3)*SW2_S + dd] = wv4.w;
  }
  __syncthreads();
  const int tx = tid&15, ty = tid>>4;
  float acc[8][4];
#pragma unroll
  for (int i=0;i<8;i++)
#pragma unroll
    for (int j=0;j<4;j++) acc[i][j]=0.f;
  for (int k=0;k<64;k++){
    float xv[8], wv[4];
    *(float2*)&xv[0] = *(const float2*)&sXT[k*SXT_S + ty*8 + 0];
    *(float2*)&xv[2] = *(const float2*)&sXT[k*SXT_S + ty*8 + 2];
    *(float2*)&xv[4] = *(const float2*)&sXT[k*SXT_S + ty*8 + 4];
    *(float2*)&xv[6] = *(const float2*)&sXT[k*SXT_S + ty*8 + 6];
    *(float2*)&wv[0] = *(const float2*)&sW2[k*SW2_S + tx*4 + 0];
    *(float2*)&wv[2] = *(const float2*)&sW2[k*SW2_S + tx*4 + 2];
#pragma unroll
    for (int i=0;i<8;i++)
#pragma unroll
      for (int j=0;j<4;j++) acc[i][j] = fmaf(xv[i], wv[j], acc[i][j]);
  }
  const float4 b4 = *(const float4*)(bias + d0 + tx*4);
  const float b2[4] = {2.f*b4.x, 2.f*b4.y, 2.f*b4.z, 2.f*b4.w};
#pragma unroll
  for (int i=0;i<8;i++){
    const int row = r0 + ty*8 + i;
    float4 o;
    float* op = (float*)&o;
#pragma unroll
    for (int j=0;j<4;j++){
      const float xq = acc[i][j] + b2[j];
      op[j] = (xq>20.f) ? xq : log1pf(expf(xq));
    }
    *(float4*)(delta + (size_t)row*DINNER + d0 + tx*4) = o;
  }
}

// ---------- chunked selective scan ----------
__global__ __launch_bounds__(256) void scan1_k(const float* __restrict__ delta,
    const float* __restrict__ xc, const float* __restrict__ xdbl,
    const float* __restrict__ A_log, float* __restrict__ hloc, float* __restrict__ Ssum){
  __shared__ float sB[TC][16];
  const int tid = threadIdx.x;
  const int d = blockIdx.x*256 + tid;
  const int c = blockIdx.y, b = blockIdx.z;
  const int row0 = b*SEQ + c*TC;
  for (int i=tid;i<TC*16;i+=256){
    int t=i>>4, j=i&15;
    sB[t][j] = xdbl[(size_t)(row0+t)*NDBL + DTRANK + j];
  }
  __syncthreads();
  float a[16];
  const f32x4* Ap = (const f32x4*)(A_log + (size_t)d*16);
#pragma unroll
  for (int q=0;q<4;q++){
    f32x4 av = Ap[q];
#pragma unroll
    for (int j=0;j<4;j++) a[q*4+j] = -__expf(av[j]);
  }
  float h[16];
#pragma unroll
  for (int n=0;n<16;n++) h[n]=0.f;
  float S = 0.f;
  float dl = delta[(size_t)row0*DINNER + d];
  float xv = xc[(size_t)row0*DINNER + d];
  for (int t=0;t<TC;t++){
    const float dlc=dl, xvc=xv;
    if (t<TC-1){
      dl = delta[(size_t)(row0+t+1)*DINNER + d];
      xv = xc[(size_t)(row0+t+1)*DINNER + d];
    }
    S += dlc;
    const float dx = dlc*xvc;
#pragma unroll
    for (int n=0;n<16;n++)
      h[n] = fmaf(__expf(dlc*a[n]), h[n], dx*sB[t][n]);
  }
  f32x4* hp = (f32x4*)(hloc + ((size_t)(b*NC+c)*DINNER + d)*16);
#pragma unroll
  for (int q=0;q<4;q++){
    f32x4 hv;
#pragma unroll
    for (int j=0;j<4;j++) hv[j]=h[q*4+j];
    hp[q]=hv;
  }
  Ssum[(size_t)(b*NC+c)*DINNER + d] = S;
}

__global__ __launch_bounds__(256) void scan2_k(const float* __restrict__ A_log,
    const float* __restrict__ Ssum, float* __restrict__ hloc){
  const int idx = blockIdx.x*256 + threadIdx.x;
  const int n = idx&15, d = (idx>>4)&(DINNER-1), b = idx>>15;
  const float a = -__expf(A_log[(size_t)d*16+n]);
  float hin = 0.f;
  for (int c=0;c<NC;c++){
    const size_t o = ((size_t)(b*NC+c)*DINNER + d)*16 + n;
    const float t = hloc[o];
    hloc[o] = hin;
    hin = fmaf(__expf(a*Ssum[(size_t)(b*NC+c)*DINNER + d]), hin, t);
  }
}

__global__ __launch_bounds__(256) void scan3_k(const float* __restrict__ delta,
    const float* __restrict__ xc, const float* __restrict__ xdbl,
    const float* __restrict__ A_log, const float* __restrict__ Dp,
    const float* __restrict__ hloc, float* __restrict__ zy){
  __shared__ float sBC[TC][32];
  const int tid = threadIdx.x;
  const int d = blockIdx.x*256 + tid;
  const int c = blockIdx.y, b = blockIdx.z;
  const int row0 = b*SEQ + c*TC;
  for (int i=tid;i<TC*32;i+=256){
    int t=i>>5, j=i&31;
    sBC[t][j] = xdbl[(size_t)(row0+t)*NDBL + DTRANK + j];
  }
  __syncthreads();
  float a[16];
  const f32x4* Ap = (const f32x4*)(A_log + (size_t)d*16);
#pragma unroll
  for (int q=0;q<4;q++){
    f32x4 av = Ap[q];
#pragma unroll
    for (int j=0;j<4;j++) a[q*4+j] = -__expf(av[j]);
  }
  float h[16];
  const f32x4* hp = (const f32x4*)(hloc + ((size_t)(b*NC+c)*DINNER + d)*16);
#pragma unroll
  for (int q=0;q<4;q++){
    f32x4 hv = hp[q];
#pragma unroll
    for (int j=0;j<4;j++) h[q*4+j]=hv[j];
  }
  const float Dv = Dp[d];
  float dl = delta[(size_t)row0*DINNER + d];
  float xv = xc[(size_t)row0*DINNER + d];
  float zv = zy[(size_t)row0*DINNER + d];
  for (int t=0;t<TC;t++){
    const float dlc=dl, xvc=xv, zvc=zv;
    if (t<TC-1){
      dl = delta[(size_t)(row0+t+1)*DINNER + d];
      xv = xc[(size_t)(row0+t+1)*DINNER + d];
      zv = zy[(size_t)(row0+t+1)*DINNER + d];
    }
    const float dx = dlc*xvc;
    float p = 0.f;
#pragma unroll
    for (int n=0;n<16;n++){
      h[n] = fmaf(__expf(dlc*a[n]), h[n], dx*sBC[t][n]);
      p = fmaf(h[n], sBC[t][16+n], p);
    }
    float y = p + xvc*Dv;
    y *= zvc/(1.f+__expf(-zvc));
    zy[(size_t)(row0+t)*DINNER + d] = y;
  }
}

extern "C" void kernel_launch(void* const* d_in, const int* in_sizes, int n_in,
                              void* d_out, int out_size, void* d_ws, size_t ws_size,
                              hipStream_t stream){
  (void)in_sizes; (void)n_in; (void)out_size; (void)ws_size;
  const float* hidden    = (const float*)d_in[0];
  const float* rms_w     = (const float*)d_in[1];
  const float* in_proj_w = (const float*)d_in[2];
  const float* x_proj_w  = (const float*)d_in[3];
  const float* out_proj_w= (const float*)d_in[4];
  const float* conv_w    = (const float*)d_in[5];
  const float* conv_b    = (const float*)d_in[6];
  const float* dt_proj_w = (const float*)d_in[7];
  const float* dt_proj_b = (const float*)d_in[8];
  const float* A_log     = (const float*)d_in[9];
  const float* Dp        = (const float*)d_in[10];

  char* ws = (char*)d_ws; size_t off = 0;
  auto alloc = [&](size_t b)->void* { void* p = ws + off; off += (b + 255) & ~(size_t)255; return p; };
  float* part3 = (float*)alloc(3*512*4);
  float* wsc   = (float*)alloc(256);
  float* RS    = (float*)alloc((size_t)ROWS*4);
  __hip_bfloat16* WQin  = (__hip_bfloat16*)alloc((size_t)4096*1024*2);
  __hip_bfloat16* WQx   = (__hip_bfloat16*)alloc((size_t)128*2048*2);
  __hip_bfloat16* WQout = (__hip_bfloat16*)alloc((size_t)1024*2048*2);
  __hip_bfloat16* QA    = (__hip_bfloat16*)alloc((size_t)ROWS*2048*2);
  float* XBUF  = (float*)alloc((size_t)ROWS*DINNER*4);
  float* ZBUF  = (float*)alloc((size_t)ROWS*DINNER*4);
  float* XC    = (float*)alloc((size_t)ROWS*DINNER*4);
  float* XDBL  = (float*)alloc((size_t)ROWS*NDBL*4);
  float* HLOC  = (float*)alloc((size_t)BATCH*NC*DINNER*16*4);
  float* SSUM  = (float*)alloc((size_t)BATCH*NC*DINNER*4);
  float* XPART = (float*)alloc((size_t)KSPLIT*ROWS*128*4);

  // weight ternarization: 3 dispatches total (incl. WQx pad zero-fill)
  absmean3_partial_k<<<dim3(512,3),256,0,stream>>>(in_proj_w, x_proj_w, out_proj_w, part3);
  absmean3_final_k<<<1,256,0,stream>>>(part3, wsc);
  {
    const int totq = N_IN_W/4 + 128*2048/4 + N_OUT_W/4;   // in + (x incl pad) + out
    ternarize3_k<<<(totq+255)/256,256,0,stream>>>(in_proj_w, x_proj_w, out_proj_w,
        (ushort*)WQin, (ushort*)WQx, (ushort*)WQout, wsc);
  }

  // 1) rms_norm + LN + act-quant of hidden
  ln_quant_k<4><<<ROWS,256,0,stream>>>(hidden, rms_w, QA, RS);
  // 2) in_proj GEMM -> x (XBUF), z (ZBUF)
  gemm2_k<128,128,1><<<dim3(ROWS/128, 4096/128, 1),256,0,stream>>>((const short*)QA,
      (const short*)WQin, RS, DIM, DIM, 0, XBUF, ZBUF, nullptr);
  // 3+4) fused conv + silu + LN + quant (writes XC and QA/RS)
  conv_ln_quant_k<<<ROWS,256,0,stream>>>(XBUF, conv_w, conv_b, XC, QA, RS);
  // 5) x_proj GEMM split-K -> partials -> combine
  gemm2_k<64,128,3><<<dim3(ROWS/64, 1, KSPLIT),256,0,stream>>>((const short*)QA,
      (const short*)WQx, nullptr, DINNER, DINNER/KSPLIT, 0, XPART, nullptr, nullptr);
  xproj_combine_k<<<(ROWS*NDBL)/256,256,0,stream>>>(XPART, RS, XDBL);
  // 6) dt_proj + softplus -> delta (reuses XBUF)
  dt_delta2_k<<<dim3(ROWS/128, DINNER/64),256,0,stream>>>(XDBL, dt_proj_w, dt_proj_b, XBUF);
  // 7) chunked selective scan; y over z in place
  scan1_k<<<dim3(DINNER/256, NC, BATCH),256,0,stream>>>(XBUF, XC, XDBL, A_log, HLOC, SSUM);
  scan2_k<<<(BATCH*DINNER*16)/256,256,0,stream>>>(A_log, SSUM, HLOC);
  scan3_k<<<dim3(DINNER/256, NC, BATCH),256,0,stream>>>(XBUF, XC, XDBL, A_log, Dp, HLOC, ZBUF);
  // 8) LN + quant of y
  ln_quant_k<8><<<ROWS,256,0,stream>>>(ZBUF, nullptr, QA, RS);
  // 9) out_proj GEMM + residual -> d_out
  gemm2_k<64,64,2><<<dim3(ROWS/64, 1024/64, 1),256,0,stream>>>((const short*)QA,
      (const short*)WQout, RS, DINNER, DINNER, DIM, (float*)d_out, nullptr, hidden);
}

// Round 7
// 180.149 us; speedup vs baseline: 4.8633x; 1.0065x over previous
//
#include <hip/hip_runtime.h>
#include <hip/hip_bf16.h>

#define BATCH 2
#define SEQ 1024
#define DIM 1024
#define DINNER 2048
#define NSTATE 16
#define DTRANK 64
#define NDBL 96
#define ROWS (BATCH*SEQ)
#define NC 32
#define TC 32
#define KSPLIT 8

#define N_IN_W  (4096*1024)
#define N_X_W   (NDBL*DINNER)
#define N_OUT_W (1024*2048)

typedef __attribute__((ext_vector_type(8))) short bf16x8;
typedef __attribute__((ext_vector_type(4))) float f32x4;

__device__ inline float wave_sum64(float v){
#pragma unroll
  for (int o=32;o>0;o>>=1) v += __shfl_xor(v,o,64);
  return v;
}
__device__ inline float wave_max64(float v){
#pragma unroll
  for (int o=32;o>0;o>>=1) v = fmaxf(v,__shfl_xor(v,o,64));
  return v;
}
__device__ inline float block_sum256(float v, float* sred){
  v = wave_sum64(v);
  if ((threadIdx.x&63)==0) sred[threadIdx.x>>6]=v;
  __syncthreads();
  float t = sred[0]+sred[1]+sred[2]+sred[3];
  __syncthreads();
  return t;
}
__device__ inline float block_max256(float v, float* sred){
  v = wave_max64(v);
  if ((threadIdx.x&63)==0) sred[threadIdx.x>>6]=v;
  __syncthreads();
  float t = fmaxf(fmaxf(sred[0],sred[1]),fmaxf(sred[2],sred[3]));
  __syncthreads();
  return t;
}

// ---------- prelude: absmean partials (1536 blk) + ln_quant<4>(hidden) (2048 blk)
// ----------          + XDBL zero (192 blk). All partitions independent.
__global__ __launch_bounds__(256) void prelude_k(
    const float* __restrict__ w0, const float* __restrict__ w1,
    const float* __restrict__ w2, float* __restrict__ part,
    const float* __restrict__ hidden, const float* __restrict__ rmsw,
    __hip_bfloat16* __restrict__ q, float* __restrict__ rs,
    float* __restrict__ xdbl_zero)
{
  __shared__ float sred[4];
  const int bid = blockIdx.x, tid = threadIdx.x;
  if (bid < 1536){
    const int wsel = bid >> 9, bx = bid & 511;
    const float* w; int n;
    if (wsel==0){ w=w0; n=N_IN_W; }
    else if (wsel==1){ w=w1; n=N_X_W; }
    else { w=w2; n=N_OUT_W; }
    float s = 0.f;
    for (int i = bx*256 + tid; i < n; i += 512*256) s += fabsf(w[i]);
    s = block_sum256(s, sred);
    if (tid==0) part[wsel*512 + bx] = s;
    return;
  }
  if (bid < 3584){
    // ln_quant<4> on hidden row r (verbatim arithmetic of ln_quant_k<4> w/ rms)
    const int r = bid - 1536;
    const float* row = hidden + (size_t)r*1024;
    float v[4];
#pragma unroll
    for (int i=0;i<4;i++) v[i] = row[tid + i*256];
    float ss=0.f;
#pragma unroll
    for (int i=0;i<4;i++) ss += v[i]*v[i];
    ss = block_sum256(ss, sred);
    float f = rsqrtf(ss/1024.f + 1e-6f);
#pragma unroll
    for (int i=0;i<4;i++) v[i] *= f * rmsw[tid + i*256];
    float s=0.f;
#pragma unroll
    for (int i=0;i<4;i++) s += v[i];
    s = block_sum256(s, sred);
    const float mu = s/1024.f;
    float vs=0.f;
#pragma unroll
    for (int i=0;i<4;i++){ float d=v[i]-mu; vs += d*d; }
    vs = block_sum256(vs, sred);
    const float inv = rsqrtf(vs/1024.f + 1e-5f);
    float am=0.f;
#pragma unroll
    for (int i=0;i<4;i++){ v[i] = (v[i]-mu)*inv; am = fmaxf(am, fabsf(v[i])); }
    am = block_max256(am, sred);
    am = fmaxf(am, 1e-5f);
    const float scale = 127.f/am;
    if (tid==0) rs[r] = am*(1.f/127.f);
#pragma unroll
    for (int i=0;i<4;i++){
      float qv = fminf(fmaxf(rintf(v[i]*scale), -128.f), 127.f);
      q[(size_t)r*1024 + tid + i*256] = __float2bfloat16(qv);
    }
    return;
  }
  // zero XDBL (ROWS*NDBL floats = 49152 float4)
  {
    const int idx = (bid - 3584)*256 + tid;
    ((float4*)xdbl_zero)[idx] = (float4){0.f,0.f,0.f,0.f};
  }
}

// ---------- ternarize all 3 weights + WQx pad; scales re-derived per block ----------
__device__ inline void tern4(const float* __restrict__ w, ushort* __restrict__ wq,
                             int i, float s){
  const float4 v = ((const float4*)w)[i];
  float q0 = fminf(fmaxf(rintf(v.x/s),-1.f),1.f);
  float q1 = fminf(fmaxf(rintf(v.y/s),-1.f),1.f);
  float q2 = fminf(fmaxf(rintf(v.z/s),-1.f),1.f);
  float q3 = fminf(fmaxf(rintf(v.w/s),-1.f),1.f);
  __hip_bfloat16 h0=__float2bfloat16(q0), h1=__float2bfloat16(q1);
  __hip_bfloat16 h2=__float2bfloat16(q2), h3=__float2bfloat16(q3);
  ushort4 o;
  o.x=*(ushort*)&h0; o.y=*(ushort*)&h1; o.z=*(ushort*)&h2; o.w=*(ushort*)&h3;
  ((ushort4*)wq)[i]=o;
}
__global__ __launch_bounds__(256) void ternarize3b_k(const float* __restrict__ w0,
    const float* __restrict__ w1, const float* __restrict__ w2,
    ushort* __restrict__ q0, ushort* __restrict__ q1, ushort* __restrict__ q2,
    const float* __restrict__ part){
  __shared__ float sred[4];
  float sc[3];
#pragma unroll
  for (int w=0; w<3; w++){
    float s = part[w*512 + threadIdx.x] + part[w*512 + threadIdx.x + 256];
    s = block_sum256(s, sred);
    const float c = (w==0)?(float)N_IN_W:((w==1)?(float)N_X_W:(float)N_OUT_W);
    sc[w] = fmaxf(s/c, 1e-5f);
  }
  const int NQ0 = N_IN_W/4, NQ1 = N_X_W/4, PQ1 = (128*2048 - N_X_W)/4, NQ2 = N_OUT_W/4;
  int i = blockIdx.x*256 + threadIdx.x;
  if (i < NQ0){ tern4(w0, q0, i, sc[0]); return; }
  i -= NQ0;
  if (i < NQ1){ tern4(w1, q1, i, sc[1]); return; }
  i -= NQ1;
  if (i < PQ1){ ((ushort4*)q1)[NQ1 + i] = (ushort4){0,0,0,0}; return; }
  i -= PQ1;
  if (i < NQ2){ tern4(w2, q2, i, sc[2]); }
}

// ---------- fused depthwise causal conv1d + silu + LayerNorm + act quant ----------
__global__ __launch_bounds__(256) void conv_ln_quant_k(const float* __restrict__ x,
    const float* __restrict__ cw, const float* __restrict__ cb,
    float* __restrict__ xc, __hip_bfloat16* __restrict__ q, float* __restrict__ rs){
  __shared__ float sred[4];
  const int r = blockIdx.x, tid = threadIdx.x;
  const int t = r & (SEQ-1);
  float v[8];
#pragma unroll
  for (int i=0;i<8;i++){
    const int d = tid + i*256;
    const float4 w4 = ((const float4*)cw)[d];
    const float wj[4] = {w4.x, w4.y, w4.z, w4.w};
    float acc = cb[d];
#pragma unroll
    for (int j=0;j<4;j++){
      const int tt = t-3+j;
      if (tt>=0) acc += x[(size_t)(r-3+j)*DINNER + d]*wj[j];
    }
    acc = acc/(1.f+expf(-acc));
    xc[(size_t)r*DINNER + d] = acc;
    v[i] = acc;
  }
  float s=0.f;
#pragma unroll
  for (int i=0;i<8;i++) s += v[i];
  s = block_sum256(s, sred);
  const float mu = s/2048.f;
  float vs=0.f;
#pragma unroll
  for (int i=0;i<8;i++){ float d=v[i]-mu; vs += d*d; }
  vs = block_sum256(vs, sred);
  const float inv = rsqrtf(vs/2048.f + 1e-5f);
  float am=0.f;
#pragma unroll
  for (int i=0;i<8;i++){ v[i] = (v[i]-mu)*inv; am = fmaxf(am, fabsf(v[i])); }
  am = block_max256(am, sred);
  am = fmaxf(am, 1e-5f);
  const float scale = 127.f/am;
  if (tid==0) rs[r] = am*(1.f/127.f);
#pragma unroll
  for (int i=0;i<8;i++){
    float qv = fminf(fmaxf(rintf(v[i]*scale), -128.f), 127.f);
    q[(size_t)r*2048 + tid + i*256] = __float2bfloat16(qv);
  }
}

// ---------- plain LN + quant (y path) ----------
__global__ __launch_bounds__(256) void ln_quant8_k(const float* __restrict__ src,
    __hip_bfloat16* __restrict__ q, float* __restrict__ rs){
  __shared__ float sred[4];
  const int r = blockIdx.x, tid = threadIdx.x;
  const float* row = src + (size_t)r*2048;
  float v[8];
#pragma unroll
  for (int i=0;i<8;i++) v[i] = row[tid + i*256];
  float s=0.f;
#pragma unroll
  for (int i=0;i<8;i++) s += v[i];
  s = block_sum256(s, sred);
  const float mu = s/2048.f;
  float vs=0.f;
#pragma unroll
  for (int i=0;i<8;i++){ float d=v[i]-mu; vs += d*d; }
  vs = block_sum256(vs, sred);
  const float inv = rsqrtf(vs/2048.f + 1e-5f);
  float am=0.f;
#pragma unroll
  for (int i=0;i<8;i++){ v[i] = (v[i]-mu)*inv; am = fmaxf(am, fabsf(v[i])); }
  am = block_max256(am, sred);
  am = fmaxf(am, 1e-5f);
  const float scale = 127.f/am;
  if (tid==0) rs[r] = am*(1.f/127.f);
#pragma unroll
  for (int i=0;i<8;i++){
    float qv = fminf(fmaxf(rintf(v[i]*scale), -128.f), 127.f);
    q[(size_t)r*2048 + tid + i*256] = __float2bfloat16(qv);
  }
}

// ---------- bf16 MFMA GEMM, BK=64, swizzled LDS ----------
// MODE 1: split cols -> out0/out1; MODE 2: out0 = hid + rs*acc; MODE 4: atomicAdd raw
template<int BM, int BN, int MODE>
__global__ __launch_bounds__(256) void gemm2_k(
    const short* __restrict__ A, const short* __restrict__ Bw,
    const float* __restrict__ rs, int K, int Ksub, int ldc,
    float* __restrict__ out0, float* __restrict__ out1,
    const float* __restrict__ hid)
{
  constexpr int MF = BM/32;
  constexpr int NF = BN/32;
  constexpr int CA = BM/32;
  constexpr int CB = BN/32;
  __shared__ short lsA[BM*64];
  __shared__ short lsB[BN*64];
  const int tid = threadIdx.x;
  const int w = tid>>6, l = tid&63;
  const int m0 = blockIdx.x*BM, n0 = blockIdx.y*BN;
  const int wr = (w>>1)*(BM/2), wc = (w&1)*(BN/2);
  const int lr = l&15, g = l>>4;
  f32x4 acc[MF][NF];
#pragma unroll
  for (int m=0;m<MF;m++)
#pragma unroll
    for (int n=0;n<NF;n++) acc[m][n] = (f32x4){0.f,0.f,0.f,0.f};

  const size_t KB = (size_t)K*2;
  const char* Ag = (const char*)A + (size_t)m0*KB + (size_t)blockIdx.z*Ksub*2;
  const char* Bg = (const char*)Bw + (size_t)n0*KB + (size_t)blockIdx.z*Ksub*2;

  bf16x8 ra[CA], rb[CB];
#define LDG(kb)                                                                   \
  {                                                                               \
    _Pragma("unroll")                                                             \
    for (int c=0;c<CA;c++){ int o=c*4096+tid*16; int rw=o>>7, cl=o&127;           \
      ra[c] = *(const bf16x8*)(Ag + (size_t)rw*KB + (size_t)(kb)*2 + cl); }       \
    _Pragma("unroll")                                                             \
    for (int c=0;c<CB;c++){ int o=c*4096+tid*16; int rw=o>>7, cl=o&127;           \
      rb[c] = *(const bf16x8*)(Bg + (size_t)rw*KB + (size_t)(kb)*2 + cl); }       \
  }

  LDG(0);
  for (int kb=0; kb<Ksub; kb+=64){
    __syncthreads();
#pragma unroll
    for (int c=0;c<CA;c++){ int o=c*4096+tid*16; int rw=o>>7, sl=(o>>4)&7;
      *(bf16x8*)((char*)lsA + (rw<<7) + ((sl^(rw&7))<<4)) = ra[c]; }
#pragma unroll
    for (int c=0;c<CB;c++){ int o=c*4096+tid*16; int rw=o>>7, sl=(o>>4)&7;
      *(bf16x8*)((char*)lsB + (rw<<7) + ((sl^(rw&7))<<4)) = rb[c]; }
    __syncthreads();
    if (kb + 64 < Ksub) LDG(kb+64);
#pragma unroll
    for (int ks=0;ks<2;ks++){
      bf16x8 af[MF], bb[NF];
#pragma unroll
      for (int m=0;m<MF;m++){ int rw = wr + m*16 + lr;
        af[m] = *(const bf16x8*)((const char*)lsA + (rw<<7) + ((((ks<<2)+g)^(lr&7))<<4)); }
#pragma unroll
      for (int n=0;n<NF;n++){ int rw = wc + n*16 + lr;
        bb[n] = *(const bf16x8*)((const char*)lsB + (rw<<7) + ((((ks<<2)+g)^(lr&7))<<4)); }
#pragma unroll
      for (int m=0;m<MF;m++)
#pragma unroll
        for (int n=0;n<NF;n++)
          acc[m][n] = __builtin_amdgcn_mfma_f32_16x16x32_bf16(af[m], bb[n], acc[m][n], 0, 0, 0);
    }
  }
#undef LDG

#pragma unroll
  for (int m=0;m<MF;m++){
    const int rowb = m0 + wr + m*16 + g*4;
#pragma unroll
    for (int j=0;j<4;j++){
      const int row = rowb + j;
      const float rsv = (MODE==4) ? 1.f : rs[row];
#pragma unroll
      for (int n=0;n<NF;n++){
        const int col = n0 + wc + n*16 + lr;
        const float v = acc[m][n][j]*rsv;
        if (MODE==1){
          if (col < 2048) out0[(size_t)row*2048 + col] = v;
          else            out1[(size_t)row*2048 + (col-2048)] = v;
        } else if (MODE==2){
          const size_t o = (size_t)row*ldc + col;
          out0[o] = hid[o] + v;
        } else {  // MODE 4: raw integer partial -> exact fp32 atomic accumulate
          if (col < NDBL) atomicAdd(&out0[(size_t)row*NDBL + col], v);
        }
      }
    }
  }
}

// ---------- dt_proj + softplus, register-blocked; consumes raw xdbl * rs ----------
#define SXT_S 130
#define SW2_S 66
__global__ __launch_bounds__(256) void dt_delta2_k(const float* __restrict__ xdbl,
    const float* __restrict__ rs,
    const float* __restrict__ W, const float* __restrict__ bias, float* __restrict__ delta){
  __shared__ float sXT[64*SXT_S];
  __shared__ float sW2[64*SW2_S];
  const int tid = threadIdx.x;
  const int r0 = blockIdx.x*128, d0 = blockIdx.y*64;
#pragma unroll
  for (int qit=0;qit<8;qit++){
    const int f4 = qit*256 + tid;
    const int rr = f4>>4, k0 = (f4&15)<<2;
    const float rsv = rs[r0+rr];
    const float4 xv4 = *(const float4*)(xdbl + (size_t)(r0+rr)*NDBL + k0);
    sXT[(k0+0)*SXT_S + rr] = xv4.x*rsv;
    sXT[(k0+1)*SXT_S + rr] = xv4.y*rsv;
    sXT[(k0+2)*SXT_S + rr] = xv4.z*rsv;
    sXT[(k0+3)*SXT_S + rr] = xv4.w*rsv;
  }
#pragma unroll
  for (int qit=0;qit<4;qit++){
    const int f4 = qit*256 + tid;
    const int dd = f4>>4, k0 = (f4&15)<<2;
    const float4 wv4 = *(const float4*)(W + (size_t)(d0+dd)*64 + k0);
    sW2[(k0+0)*SW2_S + dd] = wv4.x;
    sW2[(k0+1)*SW2_S + dd] = wv4.y;
    sW2[(k0+2)*SW2_S + dd] = wv4.z;
    sW2[(k0+3)*SW2_S + dd] = wv4.w;
  }
  __syncthreads();
  const int tx = tid&15, ty = tid>>4;
  float acc[8][4];
#pragma unroll
  for (int i=0;i<8;i++)
#pragma unroll
    for (int j=0;j<4;j++) acc[i][j]=0.f;
  for (int k=0;k<64;k++){
    float xv[8], wv[4];
    *(float2*)&xv[0] = *(const float2*)&sXT[k*SXT_S + ty*8 + 0];
    *(float2*)&xv[2] = *(const float2*)&sXT[k*SXT_S + ty*8 + 2];
    *(float2*)&xv[4] = *(const float2*)&sXT[k*SXT_S + ty*8 + 4];
    *(float2*)&xv[6] = *(const float2*)&sXT[k*SXT_S + ty*8 + 6];
    *(float2*)&wv[0] = *(const float2*)&sW2[k*SW2_S + tx*4 + 0];
    *(float2*)&wv[2] = *(const float2*)&sW2[k*SW2_S + tx*4 + 2];
#pragma unroll
    for (int i=0;i<8;i++)
#pragma unroll
      for (int j=0;j<4;j++) acc[i][j] = fmaf(xv[i], wv[j], acc[i][j]);
  }
  const float4 b4 = *(const float4*)(bias + d0 + tx*4);
  const float b2[4] = {2.f*b4.x, 2.f*b4.y, 2.f*b4.z, 2.f*b4.w};
#pragma unroll
  for (int i=0;i<8;i++){
    const int row = r0 + ty*8 + i;
    float4 o;
    float* op = (float*)&o;
#pragma unroll
    for (int j=0;j<4;j++){
      const float xq = acc[i][j] + b2[j];
      op[j] = (xq>20.f) ? xq : log1pf(expf(xq));
    }
    *(float4*)(delta + (size_t)row*DINNER + d0 + tx*4) = o;
  }
}

// ---------- chunked selective scan (B/C from raw xdbl * rs) ----------
__global__ __launch_bounds__(256) void scan1_k(const float* __restrict__ delta,
    const float* __restrict__ xc, const float* __restrict__ xdbl,
    const float* __restrict__ rs,
    const float* __restrict__ A_log, float* __restrict__ hloc, float* __restrict__ Ssum){
  __shared__ float sB[TC][16];
  const int tid = threadIdx.x;
  const int d = blockIdx.x*256 + tid;
  const int c = blockIdx.y, b = blockIdx.z;
  const int row0 = b*SEQ + c*TC;
  for (int i=tid;i<TC*16;i+=256){
    int t=i>>4, j=i&15;
    sB[t][j] = xdbl[(size_t)(row0+t)*NDBL + DTRANK + j] * rs[row0+t];
  }
  __syncthreads();
  float a[16];
  const f32x4* Ap = (const f32x4*)(A_log + (size_t)d*16);
#pragma unroll
  for (int q=0;q<4;q++){
    f32x4 av = Ap[q];
#pragma unroll
    for (int j=0;j<4;j++) a[q*4+j] = -__expf(av[j]);
  }
  float h[16];
#pragma unroll
  for (int n=0;n<16;n++) h[n]=0.f;
  float S = 0.f;
  float dl = delta[(size_t)row0*DINNER + d];
  float xv = xc[(size_t)row0*DINNER + d];
  for (int t=0;t<TC;t++){
    const float dlc=dl, xvc=xv;
    if (t<TC-1){
      dl = delta[(size_t)(row0+t+1)*DINNER + d];
      xv = xc[(size_t)(row0+t+1)*DINNER + d];
    }
    S += dlc;
    const float dx = dlc*xvc;
#pragma unroll
    for (int n=0;n<16;n++)
      h[n] = fmaf(__expf(dlc*a[n]), h[n], dx*sB[t][n]);
  }
  f32x4* hp = (f32x4*)(hloc + ((size_t)(b*NC+c)*DINNER + d)*16);
#pragma unroll
  for (int q=0;q<4;q++){
    f32x4 hv;
#pragma unroll
    for (int j=0;j<4;j++) hv[j]=h[q*4+j];
    hp[q]=hv;
  }
  Ssum[(size_t)(b*NC+c)*DINNER + d] = S;
}

__global__ __launch_bounds__(256) void scan2_k(const float* __restrict__ A_log,
    const float* __restrict__ Ssum, float* __restrict__ hloc){
  const int idx = blockIdx.x*256 + threadIdx.x;
  const int n = idx&15, d = (idx>>4)&(DINNER-1), b = idx>>15;
  const float a = -__expf(A_log[(size_t)d*16+n]);
  float hin = 0.f;
  for (int c=0;c<NC;c++){
    const size_t o = ((size_t)(b*NC+c)*DINNER + d)*16 + n;
    const float t = hloc[o];
    hloc[o] = hin;
    hin = fmaf(__expf(a*Ssum[(size_t)(b*NC+c)*DINNER + d]), hin, t);
  }
}

__global__ __launch_bounds__(256) void scan3_k(const float* __restrict__ delta,
    const float* __restrict__ xc, const float* __restrict__ xdbl,
    const float* __restrict__ rs,
    const float* __restrict__ A_log, const float* __restrict__ Dp,
    const float* __restrict__ hloc, float* __restrict__ zy){
  __shared__ float sBC[TC][32];
  const int tid = threadIdx.x;
  const int d = blockIdx.x*256 + tid;
  const int c = blockIdx.y, b = blockIdx.z;
  const int row0 = b*SEQ + c*TC;
  for (int i=tid;i<TC*32;i+=256){
    int t=i>>5, j=i&31;
    sBC[t][j] = xdbl[(size_t)(row0+t)*NDBL + DTRANK + j] * rs[row0+t];
  }
  __syncthreads();
  float a[16];
  const f32x4* Ap = (const f32x4*)(A_log + (size_t)d*16);
#pragma unroll
  for (int q=0;q<4;q++){
    f32x4 av = Ap[q];
#pragma unroll
    for (int j=0;j<4;j++) a[q*4+j] = -__expf(av[j]);
  }
  float h[16];
  const f32x4* hp = (const f32x4*)(hloc + ((size_t)(b*NC+c)*DINNER + d)*16);
#pragma unroll
  for (int q=0;q<4;q++){
    f32x4 hv = hp[q];
#pragma unroll
    for (int j=0;j<4;j++) h[q*4+j]=hv[j];
  }
  const float Dv = Dp[d];
  float dl = delta[(size_t)row0*DINNER + d];
  float xv = xc[(size_t)row0*DINNER + d];
  float zv = zy[(size_t)row0*DINNER + d];
  for (int t=0;t<TC;t++){
    const float dlc=dl, xvc=xv, zvc=zv;
    if (t<TC-1){
      dl = delta[(size_t)(row0+t+1)*DINNER + d];
      xv = xc[(size_t)(row0+t+1)*DINNER + d];
      zv = zy[(size_t)(row0+t+1)*DINNER + d];
    }
    const float dx = dlc*xvc;
    float p = 0.f;
#pragma unroll
    for (int n=0;n<16;n++){
      h[n] = fmaf(__expf(dlc*a[n]), h[n], dx*sBC[t][n]);
      p = fmaf(h[n], sBC[t][16+n], p);
    }
    float y = p + xvc*Dv;
    y *= zvc/(1.f+__expf(-zvc));
    zy[(size_t)(row0+t)*DINNER + d] = y;
  }
}

extern "C" void kernel_launch(void* const* d_in, const int* in_sizes, int n_in,
                              void* d_out, int out_size, void* d_ws, size_t ws_size,
                              hipStream_t stream){
  (void)in_sizes; (void)n_in; (void)out_size; (void)ws_size;
  const float* hidden    = (const float*)d_in[0];
  const float* rms_w     = (const float*)d_in[1];
  const float* in_proj_w = (const float*)d_in[2];
  const float* x_proj_w  = (const float*)d_in[3];
  const float* out_proj_w= (const float*)d_in[4];
  const float* conv_w    = (const float*)d_in[5];
  const float* conv_b    = (const float*)d_in[6];
  const float* dt_proj_w = (const float*)d_in[7];
  const float* dt_proj_b = (const float*)d_in[8];
  const float* A_log     = (const float*)d_in[9];
  const float* Dp        = (const float*)d_in[10];

  char* ws = (char*)d_ws; size_t off = 0;
  auto alloc = [&](size_t b)->void* { void* p = ws + off; off += (b + 255) & ~(size_t)255; return p; };
  float* part3 = (float*)alloc(3*512*4);
  float* RS    = (float*)alloc((size_t)ROWS*4);
  __hip_bfloat16* WQin  = (__hip_bfloat16*)alloc((size_t)4096*1024*2);
  __hip_bfloat16* WQx   = (__hip_bfloat16*)alloc((size_t)128*2048*2);
  __hip_bfloat16* WQout = (__hip_bfloat16*)alloc((size_t)1024*2048*2);
  __hip_bfloat16* QA    = (__hip_bfloat16*)alloc((size_t)ROWS*2048*2);
  float* XBUF  = (float*)alloc((size_t)ROWS*DINNER*4);   // pre-conv x; later delta
  float* ZBUF  = (float*)alloc((size_t)ROWS*DINNER*4);   // z; y in place
  float* XC    = (float*)alloc((size_t)ROWS*DINNER*4);   // post conv+silu x
  float* XDBL  = (float*)alloc((size_t)ROWS*NDBL*4);     // raw x_proj sums (atomic)
  float* HLOC  = (float*)alloc((size_t)BATCH*NC*DINNER*16*4);
  float* SSUM  = (float*)alloc((size_t)BATCH*NC*DINNER*4);

  // 1) prelude: absmean partials + ln_quant(hidden) + XDBL zero   [3776 blocks]
  prelude_k<<<3776,256,0,stream>>>(in_proj_w, x_proj_w, out_proj_w, part3,
                                   hidden, rms_w, QA, RS, XDBL);
  // 2) ternarize all weights (scales re-derived per block)
  {
    const int totq = N_IN_W/4 + 128*2048/4 + N_OUT_W/4;
    ternarize3b_k<<<(totq+255)/256,256,0,stream>>>(in_proj_w, x_proj_w, out_proj_w,
        (ushort*)WQin, (ushort*)WQx, (ushort*)WQout, part3);
  }
  // 3) in_proj GEMM -> x (XBUF), z (ZBUF)
  gemm2_k<128,128,1><<<dim3(ROWS/128, 4096/128, 1),256,0,stream>>>((const short*)QA,
      (const short*)WQin, RS, DIM, DIM, 0, XBUF, ZBUF, nullptr);
  // 4) fused conv + silu + LN + quant (writes XC and QA/RS)
  conv_ln_quant_k<<<ROWS,256,0,stream>>>(XBUF, conv_w, conv_b, XC, QA, RS);
  // 5) x_proj GEMM split-K, exact atomic accumulate into XDBL (raw sums)
  gemm2_k<64,128,4><<<dim3(ROWS/64, 1, KSPLIT),256,0,stream>>>((const short*)QA,
      (const short*)WQx, nullptr, DINNER, DINNER/KSPLIT, NDBL, XDBL, nullptr, nullptr);
  // 6) dt_proj + softplus -> delta (reuses XBUF); xdbl scaled by rs on load
  dt_delta2_k<<<dim3(ROWS/128, DINNER/64),256,0,stream>>>(XDBL, RS, dt_proj_w, dt_proj_b, XBUF);
  // 7) chunked selective scan; y over z in place
  scan1_k<<<dim3(DINNER/256, NC, BATCH),256,0,stream>>>(XBUF, XC, XDBL, RS, A_log, HLOC, SSUM);
  scan2_k<<<(BATCH*DINNER*16)/256,256,0,stream>>>(A_log, SSUM, HLOC);
  scan3_k<<<dim3(DINNER/256, NC, BATCH),256,0,stream>>>(XBUF, XC, XDBL, RS, A_log, Dp, HLOC, ZBUF);
  // 8) LN + quant of y
  ln_quant8_k<<<ROWS,256,0,stream>>>(ZBUF, QA, RS);
  // 9) out_proj GEMM + residual -> d_out
  gemm2_k<64,64,2><<<dim3(ROWS/64, 1024/64, 1),256,0,stream>>>((const short*)QA,
      (const short*)WQout, RS, DINNER, DINNER, DIM, (float*)d_out, nullptr, hidden);
}